// Round 5
// baseline (10575.641 us; speedup 1.0000x reference)
//
#include <hip/hip_runtime.h>
#include <hip/hip_bf16.h>
#include <stdint.h>

// ---- problem constants ----
constexpr int LI   = 128;    // L_IN
constexpr int LO   = 64;     // L_OUT
constexpr int NB   = 32;     // batch
constexpr int HD   = 1024;   // H
constexpr int HHD  = 512;    // HH
constexpr int NLAY = 2;
constexpr int NV   = 32000;  // V_OUT
constexpr int SOST = 1;

// All float tensors are FP32. Compute uses bf16x3 split MFMA (~fp32 precision).

typedef __hip_bfloat16 bf16;
typedef __attribute__((ext_vector_type(8))) short bf16x8;
typedef __attribute__((ext_vector_type(4))) float f32x4;

__device__ __forceinline__ float b2f(bf16 x) { return __bfloat162float(x); }
__device__ __forceinline__ bf16  f2b(float x) { return __float2bfloat16(x); }
__device__ __forceinline__ float sigm(float x) { return 1.0f / (1.0f + expf(-x)); }

__device__ __forceinline__ f32x4 mfma(bf16x8 a, bf16x8 b, f32x4 c) {
    return __builtin_amdgcn_mfma_f32_16x16x32_bf16(a, b, c, 0, 0, 0);
}
// split product: (ah+al)*(bh+bl) ~= ah*bh + ah*bl + al*bh
__device__ __forceinline__ f32x4 mfma3(bf16x8 ah, bf16x8 al, bf16x8 bh, bf16x8 bl, f32x4 c) {
    c = mfma(ah, bh, c);
    c = mfma(ah, bl, c);
    c = mfma(al, bh, c);
    return c;
}
__device__ __forceinline__ bf16x8 ld8(const bf16* p) { return *(const bf16x8*)p; }

__device__ __forceinline__ void split8(const float* p, bf16x8& h8, bf16x8& l8) {
    #pragma unroll
    for (int j = 0; j < 8; j++) {
        float v = p[j];
        bf16 h = f2b(v);
        bf16 l = f2b(v - b2f(h));
        ((bf16*)&h8)[j] = h;
        ((bf16*)&l8)[j] = l;
    }
}

// ---- grid barrier (persistent kernels; one counter per step, pre-zeroed) ----
__device__ __forceinline__ void gbar(int* b, int nb) {
    __syncthreads();
    if (threadIdx.x == 0) {
        __threadfence();   // release: my h-state stores visible device-wide
        __hip_atomic_fetch_add(b, 1, __ATOMIC_RELAXED, __HIP_MEMORY_SCOPE_AGENT);
        while (__hip_atomic_load(b, __ATOMIC_RELAXED, __HIP_MEMORY_SCOPE_AGENT) < nb)
            __builtin_amdgcn_s_sleep(2);
        __threadfence();   // acquire: invalidate caches before reading peers' data
    }
    __syncthreads();
}

// =====================================================================
// Split-precision MFMA GEMM: C[m,n] = sum_k A[m,k]*W[n,k] (+bias) (opt tanh)
// A,W,C fp32. 128-wide N tile, BM in {64,128}. 4 waves. z-batched.
// =====================================================================
template<int BM, bool BIAS, bool TANH>
__global__ __launch_bounds__(256) void gemm_k(
    const float* __restrict__ A, int64_t lda, int64_t sA,
    const float* __restrict__ W, int64_t ldw, int64_t sW,
    float* __restrict__ C, int64_t ldc, int64_t sC,
    const float* __restrict__ bias, int64_t sBias,
    int K)
{
    constexpr int FM = BM / 32;
    __shared__ __align__(16) bf16 Ahi[BM * 32], Alo[BM * 32];
    __shared__ __align__(16) bf16 Whi[128 * 32], Wlo[128 * 32];
    const int z    = blockIdx.z;
    const float* Ab = A + (int64_t)z * sA;
    const float* Wb = W + (int64_t)z * sW;
    const int n0   = blockIdx.x * 128;
    const int m0   = blockIdx.y * BM;
    const int tid  = threadIdx.x;
    const int lane = tid & 63, wid = tid >> 6;
    const int wm   = wid >> 1, wn = wid & 1;
    const int srow = lane >> 2;
    const int skb  = (lane & 3) * 8;
    const int r16  = lane & 15;
    const int k8   = (lane >> 4) * 8;

    f32x4 acc[FM][4];
    #pragma unroll
    for (int i = 0; i < FM; i++)
        #pragma unroll
        for (int j = 0; j < 4; j++)
            acc[i][j] = f32x4{0.f, 0.f, 0.f, 0.f};

    for (int k0 = 0; k0 < K; k0 += 32) {
        for (int c = wid; c < BM / 16; c += 4) {
            bf16x8 h8, l8;
            split8(Ab + (int64_t)(m0 + c * 16 + srow) * lda + k0 + skb, h8, l8);
            *(bf16x8*)(Ahi + c * 512 + lane * 8) = h8;
            *(bf16x8*)(Alo + c * 512 + lane * 8) = l8;
        }
        for (int c = wid; c < 8; c += 4) {
            bf16x8 h8, l8;
            split8(Wb + (int64_t)(n0 + c * 16 + srow) * ldw + k0 + skb, h8, l8);
            *(bf16x8*)(Whi + c * 512 + lane * 8) = h8;
            *(bf16x8*)(Wlo + c * 512 + lane * 8) = l8;
        }
        __syncthreads();
        bf16x8 afh[FM], afl[FM], wfh[4], wfl[4];
        #pragma unroll
        for (int mt = 0; mt < FM; mt++) {
            const int off = (wm * (BM / 2) + mt * 16 + r16) * 32 + k8;
            afh[mt] = ld8(Ahi + off);
            afl[mt] = ld8(Alo + off);
        }
        #pragma unroll
        for (int nt = 0; nt < 4; nt++) {
            const int off = (wn * 64 + nt * 16 + r16) * 32 + k8;
            wfh[nt] = ld8(Whi + off);
            wfl[nt] = ld8(Wlo + off);
        }
        #pragma unroll
        for (int mt = 0; mt < FM; mt++)
            #pragma unroll
            for (int nt = 0; nt < 4; nt++)
                acc[mt][nt] = mfma3(afh[mt], afl[mt], wfh[nt], wfl[nt], acc[mt][nt]);
        __syncthreads();
    }
    #pragma unroll
    for (int nt = 0; nt < 4; nt++) {
        const int n = n0 + wn * 64 + nt * 16 + r16;
        float bv = 0.f;
        if constexpr (BIAS) bv = bias[(int64_t)z * sBias + n];
        #pragma unroll
        for (int mt = 0; mt < FM; mt++) {
            const int mb = m0 + wm * (BM / 2) + mt * 16 + (lane >> 4) * 4;
            #pragma unroll
            for (int r = 0; r < 4; r++) {
                float v = acc[mt][nt][r] + bv;
                if constexpr (TANH) v = tanhf(v);
                C[(int64_t)z * sC + (int64_t)(mb + r) * ldc + n] = v;
            }
        }
    }
}

__global__ void presplit_k(const float* __restrict__ x, bf16* __restrict__ hi,
                           bf16* __restrict__ lo, int n)
{
    const int i = blockIdx.x * 256 + threadIdx.x;
    if (i < n) {
        float v = x[i];
        bf16 h = f2b(v);
        hi[i] = h;
        lo[i] = f2b(v - b2f(h));
    }
}

__global__ void embed_k(const int* __restrict__ toks, const float* __restrict__ tab,
                        float* __restrict__ out, int shifted)
{
    const int row = blockIdx.x;
    int tok;
    if (shifted) {
        const int t = row / NB, b = row - t * NB;
        tok = (t == 0) ? SOST : toks[(t - 1) * NB + b];
    } else {
        tok = toks[row];
    }
    const uint4* s = (const uint4*)(tab + (int64_t)tok * HD);
    uint4* d = (uint4*)(out + (int64_t)row * HD);
    d[threadIdx.x] = s[threadIdx.x];
}

// =====================================================================
// Persistent encoder layer: all LI steps in one launch, grid barrier per
// step. Grid (HHD/16, 2 dirs) = 64 blocks x 1 wave. Math identical to r4.
// =====================================================================
__global__ __launch_bounds__(64) void enc_persist_k(
    const float* __restrict__ gi,     // [2][LI*NB][3*HHD] (+b_ih)
    const bf16* __restrict__ whhHi,   // [2][3*HHD][HHD] (this layer)
    const bf16* __restrict__ whhLo,
    const float* __restrict__ bhh,    // [2][3*HHD]
    float* __restrict__ h32,          // [2 par][2 dir][NB][HHD]
    bf16* __restrict__ hHi, bf16* __restrict__ hLo,
    float* __restrict__ Y,            // [LI][NB][HD]
    float* __restrict__ dh32, bf16* __restrict__ dhHi, bf16* __restrict__ dhLo,
    int* __restrict__ bar)            // [LI-1] zeroed counters
{
    const int d = blockIdx.y;
    const int j0 = blockIdx.x * 16;
    const int lane = threadIdx.x;
    const int r16 = lane & 15, k8 = (lane >> 4) * 8;
    const bf16* WdH = whhHi + (int64_t)d * 3 * HHD * HHD;
    const bf16* WdL = whhLo + (int64_t)d * 3 * HHD * HHD;
    const int j = j0 + r16;
    const float br = bhh[d * 3 * HHD + j];
    const float bz = bhh[d * 3 * HHD + HHD + j];
    const float bn = bhh[d * 3 * HHD + 2 * HHD + j];

    for (int s = 0; s < LI; s++) {
        const int t = d ? (LI - 1 - s) : s;
        const int par = s & 1, npar = par ^ 1;
        const int64_t hbase = (int64_t)(par * 2 + d) * NB * HHD;

        f32x4 acc[2][3];
        #pragma unroll
        for (int i = 0; i < 2; i++)
            #pragma unroll
            for (int g = 0; g < 3; g++) acc[i][g] = f32x4{0.f, 0.f, 0.f, 0.f};

        for (int k0 = 0; k0 < HHD; k0 += 32) {
            bf16x8 a0h = ld8(hHi + hbase + r16 * HHD + k0 + k8);
            bf16x8 a0l = ld8(hLo + hbase + r16 * HHD + k0 + k8);
            bf16x8 a1h = ld8(hHi + hbase + (16 + r16) * HHD + k0 + k8);
            bf16x8 a1l = ld8(hLo + hbase + (16 + r16) * HHD + k0 + k8);
            #pragma unroll
            for (int g = 0; g < 3; g++) {
                const int64_t wo = (int64_t)(g * HHD + j0 + r16) * HHD + k0 + k8;
                bf16x8 wh = ld8(WdH + wo);
                bf16x8 wl = ld8(WdL + wo);
                acc[0][g] = mfma3(a0h, a0l, wh, wl, acc[0][g]);
                acc[1][g] = mfma3(a1h, a1l, wh, wl, acc[1][g]);
            }
        }
        const float* gid = gi + ((int64_t)d * LI * NB + (int64_t)t * NB) * (3 * HHD);
        #pragma unroll
        for (int mt = 0; mt < 2; mt++)
            #pragma unroll
            for (int r = 0; r < 4; r++) {
                const int b = mt * 16 + (lane >> 4) * 4 + r;
                const float ir  = gid[b * 3 * HHD + j];
                const float iz  = gid[b * 3 * HHD + HHD + j];
                const float inn = gid[b * 3 * HHD + 2 * HHD + j];
                const float rg = sigm(ir + acc[mt][0][r] + br);
                const float zg = sigm(iz + acc[mt][1][r] + bz);
                const float ng = tanhf(inn + rg * (acc[mt][2][r] + bn));
                const float hold = h32[hbase + (int64_t)b * HHD + j];
                const float hnew = (1.f - zg) * ng + zg * hold;
                const int64_t no = (int64_t)(npar * 2 + d) * NB * HHD + (int64_t)b * HHD + j;
                bf16 hh = f2b(hnew);
                h32[no] = hnew;
                hHi[no] = hh;
                hLo[no] = f2b(hnew - b2f(hh));
                Y[((int64_t)t * NB + b) * HD + d * HHD + j] = hnew;
                if (s == LI - 1) {
                    const int64_t dof = (int64_t)b * HD + d * HHD + j;
                    dh32[dof] = hnew;
                    dhHi[dof] = hh;
                    dhLo[dof] = f2b(hnew - b2f(hh));
                }
            }
        if (s < LI - 1) gbar(&bar[s], 64);
    }
}

// =====================================================================
// Persistent decoder: 65 pipelined iterations (layer0@s || layer1@s-1),
// grid barrier per iteration. Grid (HD/16, 2 roles) = 128 blocks x 1 wave.
// =====================================================================
__global__ __launch_bounds__(64) void dec_persist_k(
    const float* __restrict__ gi0,    // [LO*NB][3*HD] (+b_ih0)
    const bf16* __restrict__ wih1Hi, const bf16* __restrict__ wih1Lo,
    const bf16* __restrict__ whh0Hi, const bf16* __restrict__ whh0Lo,
    const bf16* __restrict__ whh1Hi, const bf16* __restrict__ whh1Lo,
    const float* __restrict__ bih1,
    const float* __restrict__ bhh0,
    const float* __restrict__ bhh1,
    float* __restrict__ h32,          // [2 par][NLAY][NB][HD]
    bf16* __restrict__ hHi, bf16* __restrict__ hLo,
    float* __restrict__ rnn,          // [LO][NB][HD]
    int* __restrict__ bar)            // [LO] zeroed counters
{
    const int lane = threadIdx.x;
    const int r16 = lane & 15, k8 = (lane >> 4) * 8;
    const int j0 = blockIdx.x * 16;
    const int j = j0 + r16;
    const int role = blockIdx.y;

    // hoisted step-invariant biases
    const float b0r = bhh0[j], b0z = bhh0[HD + j], b0n = bhh0[2 * HD + j];
    const float brr = bih1[j] + bhh1[j];
    const float bzz = bih1[HD + j] + bhh1[HD + j];
    const float bin = bih1[2 * HD + j];
    const float bhn = bhh1[2 * HD + j];

    for (int s = 0; s <= LO; s++) {
        if (role == 0) {
            if (s < LO) {
                const int t = s, par = t & 1, npar = par ^ 1;
                const int64_t hb = (int64_t)(par * NLAY + 0) * NB * HD;
                f32x4 acc[2][3];
                #pragma unroll
                for (int i = 0; i < 2; i++)
                    #pragma unroll
                    for (int g = 0; g < 3; g++) acc[i][g] = f32x4{0.f, 0.f, 0.f, 0.f};
                for (int k0 = 0; k0 < HD; k0 += 32) {
                    bf16x8 a0h = ld8(hHi + hb + r16 * HD + k0 + k8);
                    bf16x8 a0l = ld8(hLo + hb + r16 * HD + k0 + k8);
                    bf16x8 a1h = ld8(hHi + hb + (16 + r16) * HD + k0 + k8);
                    bf16x8 a1l = ld8(hLo + hb + (16 + r16) * HD + k0 + k8);
                    #pragma unroll
                    for (int g = 0; g < 3; g++) {
                        const int64_t wo = (int64_t)(g * HD + j0 + r16) * HD + k0 + k8;
                        bf16x8 wh = ld8(whh0Hi + wo);
                        bf16x8 wl = ld8(whh0Lo + wo);
                        acc[0][g] = mfma3(a0h, a0l, wh, wl, acc[0][g]);
                        acc[1][g] = mfma3(a1h, a1l, wh, wl, acc[1][g]);
                    }
                }
                const float* gid = gi0 + (int64_t)t * NB * 3 * HD;
                #pragma unroll
                for (int mt = 0; mt < 2; mt++)
                    #pragma unroll
                    for (int r = 0; r < 4; r++) {
                        const int b = mt * 16 + (lane >> 4) * 4 + r;
                        const float ir  = gid[b * 3 * HD + j];
                        const float iz  = gid[b * 3 * HD + HD + j];
                        const float inn = gid[b * 3 * HD + 2 * HD + j];
                        const float rg = sigm(ir + acc[mt][0][r] + b0r);
                        const float zg = sigm(iz + acc[mt][1][r] + b0z);
                        const float ng = tanhf(inn + rg * (acc[mt][2][r] + b0n));
                        const float hold = h32[hb + (int64_t)b * HD + j];
                        const float hnew = (1.f - zg) * ng + zg * hold;
                        const int64_t no = (int64_t)(npar * NLAY + 0) * NB * HD + (int64_t)b * HD + j;
                        bf16 hh = f2b(hnew);
                        h32[no] = hnew;
                        hHi[no] = hh;
                        hLo[no] = f2b(hnew - b2f(hh));
                    }
            }
        } else {
            if (s >= 1) {
                const int t = s - 1;
                const int p0 = (t + 1) & 1;
                const int p1 = t & 1, np1 = p1 ^ 1;
                const int64_t h0b = (int64_t)(p0 * NLAY + 0) * NB * HD;
                const int64_t h1b = (int64_t)(p1 * NLAY + 1) * NB * HD;
                f32x4 arz[2][2], ain[2], ahn[2];
                #pragma unroll
                for (int i = 0; i < 2; i++) {
                    arz[i][0] = f32x4{0.f, 0.f, 0.f, 0.f};
                    arz[i][1] = f32x4{0.f, 0.f, 0.f, 0.f};
                    ain[i] = f32x4{0.f, 0.f, 0.f, 0.f};
                    ahn[i] = f32x4{0.f, 0.f, 0.f, 0.f};
                }
                for (int k0 = 0; k0 < HD; k0 += 32) {
                    bf16x8 x0h = ld8(hHi + h0b + r16 * HD + k0 + k8);
                    bf16x8 x0l = ld8(hLo + h0b + r16 * HD + k0 + k8);
                    bf16x8 x1h = ld8(hHi + h0b + (16 + r16) * HD + k0 + k8);
                    bf16x8 x1l = ld8(hLo + h0b + (16 + r16) * HD + k0 + k8);
                    bf16x8 y0h = ld8(hHi + h1b + r16 * HD + k0 + k8);
                    bf16x8 y0l = ld8(hLo + h1b + r16 * HD + k0 + k8);
                    bf16x8 y1h = ld8(hHi + h1b + (16 + r16) * HD + k0 + k8);
                    bf16x8 y1l = ld8(hLo + h1b + (16 + r16) * HD + k0 + k8);
                    const int64_t wr = (int64_t)(j0 + r16) * HD + k0 + k8;
                    const int64_t wz = (int64_t)(HD + j0 + r16) * HD + k0 + k8;
                    const int64_t wn = (int64_t)(2 * HD + j0 + r16) * HD + k0 + k8;
                    bf16x8 wirh = ld8(wih1Hi + wr), wirl = ld8(wih1Lo + wr);
                    bf16x8 whrh = ld8(whh1Hi + wr), whrl = ld8(whh1Lo + wr);
                    bf16x8 wizh = ld8(wih1Hi + wz), wizl = ld8(wih1Lo + wz);
                    bf16x8 whzh = ld8(whh1Hi + wz), whzl = ld8(whh1Lo + wz);
                    bf16x8 winh = ld8(wih1Hi + wn), winl = ld8(wih1Lo + wn);
                    bf16x8 whnh = ld8(whh1Hi + wn), whnl = ld8(whh1Lo + wn);
                    arz[0][0] = mfma3(x0h, x0l, wirh, wirl, arz[0][0]);
                    arz[0][0] = mfma3(y0h, y0l, whrh, whrl, arz[0][0]);
                    arz[1][0] = mfma3(x1h, x1l, wirh, wirl, arz[1][0]);
                    arz[1][0] = mfma3(y1h, y1l, whrh, whrl, arz[1][0]);
                    arz[0][1] = mfma3(x0h, x0l, wizh, wizl, arz[0][1]);
                    arz[0][1] = mfma3(y0h, y0l, whzh, whzl, arz[0][1]);
                    arz[1][1] = mfma3(x1h, x1l, wizh, wizl, arz[1][1]);
                    arz[1][1] = mfma3(y1h, y1l, whzh, whzl, arz[1][1]);
                    ain[0] = mfma3(x0h, x0l, winh, winl, ain[0]);
                    ain[1] = mfma3(x1h, x1l, winh, winl, ain[1]);
                    ahn[0] = mfma3(y0h, y0l, whnh, whnl, ahn[0]);
                    ahn[1] = mfma3(y1h, y1l, whnh, whnl, ahn[1]);
                }
                #pragma unroll
                for (int mt = 0; mt < 2; mt++)
                    #pragma unroll
                    for (int r = 0; r < 4; r++) {
                        const int b = mt * 16 + (lane >> 4) * 4 + r;
                        const float rg = sigm(arz[mt][0][r] + brr);
                        const float zg = sigm(arz[mt][1][r] + bzz);
                        const float ng = tanhf(ain[mt][r] + bin + rg * (ahn[mt][r] + bhn));
                        const float hold = h32[h1b + (int64_t)b * HD + j];
                        const float hnew = (1.f - zg) * ng + zg * hold;
                        const int64_t no = (int64_t)(np1 * NLAY + 1) * NB * HD + (int64_t)b * HD + j;
                        bf16 hh = f2b(hnew);
                        h32[no] = hnew;
                        hHi[no] = hh;
                        hLo[no] = f2b(hnew - b2f(hh));
                        rnn[((int64_t)t * NB + b) * HD + j] = hnew;
                    }
            }
        }
        if (s < LO) gbar(&bar[s], 128);
    }
}

// =====================================================================
__global__ __launch_bounds__(64) void softmax_k(const float* __restrict__ sc,
                                                float* __restrict__ aout)
{
    const int row = blockIdx.x, l = threadIdx.x;
    float v0 = sc[row * LI + l], v1 = sc[row * LI + 64 + l];
    float m = fmaxf(v0, v1);
    #pragma unroll
    for (int o = 32; o > 0; o >>= 1) m = fmaxf(m, __shfl_xor(m, o));
    float e0 = expf(v0 - m), e1 = expf(v1 - m);
    float s = e0 + e1;
    #pragma unroll
    for (int o = 32; o > 0; o >>= 1) s += __shfl_xor(s, o);
    const float inv = 1.f / s;
    aout[row * LI + l] = e0 * inv;
    aout[row * LI + 64 + l] = e1 * inv;
}

__global__ __launch_bounds__(256) void ctx_k(const float* __restrict__ at,
                                             const float* __restrict__ enc,
                                             float* __restrict__ jin)
{
    const int b = blockIdx.y, h0 = blockIdx.x * 128;
    __shared__ __align__(16) float al[LO][LI];
    for (int i = threadIdx.x; i < LO * LI; i += 256) {
        const int to = i >> 7, ti = i & 127;
        al[to][ti] = at[(to * NB + b) * LI + ti];
    }
    __syncthreads();
    const int hc = h0 + (threadIdx.x & 127);
    const int rh = threadIdx.x >> 7;
    float acc[32];
    #pragma unroll
    for (int i = 0; i < 32; i++) acc[i] = 0.f;
    for (int t = 0; t < LI; t++) {
        const float ev = enc[((int64_t)t * NB + b) * HD + hc];
        #pragma unroll
        for (int i = 0; i < 32; i++) acc[i] += ev * al[rh * 32 + i][t];
    }
    #pragma unroll
    for (int i = 0; i < 32; i++)
        jin[((int64_t)(rh * 32 + i) * NB + b) * (2 * HD) + hc] = acc[i];
}

__global__ void rnncopy_k(const float* __restrict__ rnn, float* __restrict__ jin)
{
    const int idx = blockIdx.x * 256 + threadIdx.x;
    const int row = idx >> 8;
    const int c = idx & 255;
    ((uint4*)jin)[(int64_t)row * 512 + 256 + c] = ((const uint4*)rnn)[idx];
}

// =====================================================================
extern "C" void kernel_launch(void* const* d_in, const int* in_sizes, int n_in,
                              void* d_out, int out_size, void* d_ws, size_t ws_size,
                              hipStream_t stream)
{
    (void)in_sizes; (void)n_in; (void)out_size; (void)ws_size;
    const int*   in_tok   = (const int*)d_in[0];
    const int*   out_tok  = (const int*)d_in[2];
    const float* enc_emb  = (const float*)d_in[4];
    const float* enc_wih  = (const float*)d_in[5];
    const float* enc_whh  = (const float*)d_in[6];
    const float* enc_bih  = (const float*)d_in[7];
    const float* enc_bhh  = (const float*)d_in[8];
    const float* dec_emb  = (const float*)d_in[9];
    const float* dec_wih  = (const float*)d_in[10];
    const float* dec_whh  = (const float*)d_in[11];
    const float* dec_bih  = (const float*)d_in[12];
    const float* dec_bhh  = (const float*)d_in[13];
    const float* attn_W   = (const float*)d_in[14];
    const float* joiner_W = (const float*)d_in[15];
    const float* joiner_b = (const float*)d_in[16];
    const float* proj_W   = (const float*)d_in[17];
    const float* proj_b   = (const float*)d_in[18];
    float* logits   = (float*)d_out;
    float* attn_out = logits + (size_t)LO * NB * NV;

    // ---- scratch in d_out's logits region (250 MiB): fully overwritten by
    // the final logits GEMM; attn tail untouched until softmax. VECS +
    // h-state in d_ws (10 MiB). Barrier counters at o+218MiB (zeroed here).
    const size_t MB = 1ull << 20;
    char* o = (char*)d_out;
    float* XB0   = (float*)(o);              // 16 MiB enc embedded input
    float* XB1   = (float*)(o + 16 * MB);    // 16 MiB enc layer0 output
    float* EOUT  = (float*)(o + 32 * MB);    // 16 MiB enc_outputs
    float* PENC  = (float*)(o + 48 * MB);    // 16 MiB proj_enc
    float* GI    = (float*)(o + 64 * MB);    // 48 MiB enc gi (both dirs)
    float* DEMB  = (float*)(o + 112 * MB);   //  8 MiB dec embedded
    float* DGI0  = (float*)(o + 120 * MB);   // 24 MiB dec layer0 gi
    float* RNN   = (float*)(o + 144 * MB);   //  8 MiB rnn_out
    float* SC    = (float*)(o + 152 * MB);   //  1 MiB scores
    float* JIN   = (float*)(o + 153 * MB);   // 16 MiB cat(ctx, rnn)
    bf16* WencHi = (bf16*)(o + 169 * MB);    //  6 MiB enc_whh hi
    bf16* WencLo = (bf16*)(o + 175 * MB);    //  6 MiB enc_whh lo
    bf16* WdhHi  = (bf16*)(o + 181 * MB);    // 12 MiB dec_whh hi
    bf16* WdhLo  = (bf16*)(o + 193 * MB);    // 12 MiB dec_whh lo
    bf16* Wih1Hi = (bf16*)(o + 205 * MB);    //  6 MiB dec_wih[1] hi
    bf16* Wih1Lo = (bf16*)(o + 211 * MB);    //  6 MiB dec_wih[1] lo
    int*  BAR_E0 = (int*)(o + 218 * MB);     // 128 ints
    int*  BAR_E1 = BAR_E0 + 128;             // 128 ints
    int*  BAR_D  = BAR_E0 + 256;             // 65 ints

    char* w = (char*)d_ws;                   // 10 MiB total
    float* VECS = (float*)(w);                       // 8 MiB tanh(joiner)
    float* EH32 = (float*)(w + 8 * MB);              // 512 KiB
    bf16*  EHhi = (bf16*) (w + 8 * MB + 524288);     // 256 KiB
    bf16*  EHlo = (bf16*) (w + 8 * MB + 786432);     // 256 KiB
    float* DH32 = (float*)(w + 9 * MB);              // 512 KiB
    bf16*  DHhi = (bf16*) (w + 9 * MB + 524288);     // 256 KiB
    bf16*  DHlo = (bf16*) (w + 9 * MB + 786432);     // 256 KiB

    hipMemsetAsync(BAR_E0, 0, (256 + 65) * sizeof(int), stream);

    // ---- pre-split recurrent weights ----
    const int nEnc = NLAY * 2 * 3 * HHD * HHD;
    const int nDhh = NLAY * 3 * HD * HD;
    const int nIh1 = 3 * HD * HD;
    presplit_k<<<dim3((nEnc + 255) / 256), dim3(256), 0, stream>>>(enc_whh, WencHi, WencLo, nEnc);
    presplit_k<<<dim3((nDhh + 255) / 256), dim3(256), 0, stream>>>(dec_whh, WdhHi, WdhLo, nDhh);
    presplit_k<<<dim3((nIh1 + 255) / 256), dim3(256), 0, stream>>>(dec_wih + (size_t)3 * HD * HD, Wih1Hi, Wih1Lo, nIh1);

    // ---- decoder prep ----
    embed_k<<<dim3(LO * NB), dim3(256), 0, stream>>>(out_tok, dec_emb, DEMB, 1);
    gemm_k<128, true, false><<<dim3(3 * HD / 128, LO * NB / 128, 1), 256, 0, stream>>>(
        DEMB, HD, 0, dec_wih, HD, 0, DGI0, 3 * HD, 0, dec_bih, 0, HD);

    // ---- encoder ----
    embed_k<<<dim3(LI * NB), dim3(256), 0, stream>>>(in_tok, enc_emb, XB0, 0);
    for (int l = 0; l < NLAY; l++) {
        const float* Xin = l ? XB1 : XB0;
        float* Yout = l ? EOUT : XB1;
        hipMemsetAsync(EH32, 0, (size_t)2 * 2 * NB * HHD * 4, stream);
        hipMemsetAsync(EHhi, 0, (size_t)2 * 2 * NB * HHD * 2, stream);
        hipMemsetAsync(EHlo, 0, (size_t)2 * 2 * NB * HHD * 2, stream);
        gemm_k<128, true, false><<<dim3(3 * HHD / 128, LI * NB / 128, 2), 256, 0, stream>>>(
            Xin, HD, 0,
            enc_wih + (size_t)l * 2 * 3 * HHD * HD, HD, (int64_t)3 * HHD * HD,
            GI, 3 * HHD, (int64_t)LI * NB * 3 * HHD,
            enc_bih + l * 2 * 3 * HHD, 3 * HHD, HD);
        enc_persist_k<<<dim3(HHD / 16, 2), dim3(64), 0, stream>>>(
            GI,
            WencHi + (size_t)l * 2 * 3 * HHD * HHD,
            WencLo + (size_t)l * 2 * 3 * HHD * HHD,
            enc_bhh + l * 2 * 3 * HHD,
            EH32, EHhi, EHlo, Yout,
            DH32 + (size_t)l * NB * HD, DHhi + (size_t)l * NB * HD,
            DHlo + (size_t)l * NB * HD,
            l ? BAR_E1 : BAR_E0);
    }

    // proj_enc = enc_outputs @ attn_W^T
    gemm_k<128, false, false><<<dim3(HD / 128, LI * NB / 128, 1), 256, 0, stream>>>(
        EOUT, HD, 0, attn_W, HD, 0, PENC, HD, 0, nullptr, 0, HD);

    // ---- decoder recurrence (persistent) ----
    dec_persist_k<<<dim3(HD / 16, 2), dim3(64), 0, stream>>>(
        DGI0,
        Wih1Hi, Wih1Lo,
        WdhHi, WdhLo,
        WdhHi + (size_t)3 * HD * HD, WdhLo + (size_t)3 * HD * HD,
        dec_bih + 3 * HD, dec_bhh, dec_bhh + 3 * HD,
        DH32, DHhi, DHlo, RNN, BAR_D);

    // ---- batched epilogue ----
    gemm_k<64, false, false><<<dim3(1, 1, NB), 256, 0, stream>>>(
        RNN, (int64_t)NB * HD, HD, PENC, (int64_t)NB * HD, HD,
        SC, (int64_t)NB * LI, LI, nullptr, 0, HD);
    softmax_k<<<dim3(LO * NB), dim3(64), 0, stream>>>(SC, attn_out);
    ctx_k<<<dim3(HD / 128, NB), dim3(256), 0, stream>>>(attn_out, EOUT, JIN);
    rnncopy_k<<<dim3(LO * NB * HD / 4 / 256), dim3(256), 0, stream>>>(RNN, JIN);
    gemm_k<128, true, true><<<dim3(HD / 128, LO * NB / 128, 1), 256, 0, stream>>>(
        JIN, 2 * HD, 0, joiner_W, 2 * HD, 0, VECS, HD, 0, joiner_b, 0, 2 * HD);
    gemm_k<128, true, false><<<dim3(NV / 128, LO * NB / 128, 1), 256, 0, stream>>>(
        VECS, HD, 0, proj_W, HD, 0, logits, NV, 0, proj_b, 0, HD);
}

// Round 6
// 7693.407 us; speedup vs baseline: 1.3746x; 1.3746x over previous
//
#include <hip/hip_runtime.h>
#include <hip/hip_bf16.h>
#include <stdint.h>

// ---- problem constants ----
constexpr int LI   = 128;    // L_IN
constexpr int LO   = 64;     // L_OUT
constexpr int NB   = 32;     // batch
constexpr int HD   = 1024;   // H
constexpr int HHD  = 512;    // HH
constexpr int NLAY = 2;
constexpr int NV   = 32000;  // V_OUT
constexpr int SOST = 1;

// All float tensors are FP32. Compute uses bf16x3 split MFMA (~fp32 precision).
// Persistent recurrence: W held in REGISTERS (immune to the grid-barrier's
// L2 invalidation, which round-5 counters showed refetches W from HBM/step).

typedef __hip_bfloat16 bf16;
typedef __attribute__((ext_vector_type(8))) short bf16x8;
typedef __attribute__((ext_vector_type(4))) float f32x4;

__device__ __forceinline__ float b2f(bf16 x) { return __bfloat162float(x); }
__device__ __forceinline__ bf16  f2b(float x) { return __float2bfloat16(x); }
__device__ __forceinline__ float sigm(float x) { return 1.0f / (1.0f + expf(-x)); }

__device__ __forceinline__ f32x4 mfma(bf16x8 a, bf16x8 b, f32x4 c) {
    return __builtin_amdgcn_mfma_f32_16x16x32_bf16(a, b, c, 0, 0, 0);
}
// split product: (ah+al)*(bh+bl) ~= ah*bh + ah*bl + al*bh
__device__ __forceinline__ f32x4 mfma3(bf16x8 ah, bf16x8 al, bf16x8 bh, bf16x8 bl, f32x4 c) {
    c = mfma(ah, bh, c);
    c = mfma(ah, bl, c);
    c = mfma(al, bh, c);
    return c;
}
__device__ __forceinline__ bf16x8 ld8(const bf16* p) { return *(const bf16x8*)p; }

__device__ __forceinline__ void split8(const float* p, bf16x8& h8, bf16x8& l8) {
    #pragma unroll
    for (int j = 0; j < 8; j++) {
        float v = p[j];
        bf16 h = f2b(v);
        bf16 l = f2b(v - b2f(h));
        ((bf16*)&h8)[j] = h;
        ((bf16*)&l8)[j] = l;
    }
}

// ---- grid barrier (one counter per use, pre-zeroed per call) ----
__device__ __forceinline__ void gbar(int* b, int nb) {
    __syncthreads();
    if (threadIdx.x == 0) {
        __threadfence();   // release (wbl2)
        __hip_atomic_fetch_add(b, 1, __ATOMIC_RELAXED, __HIP_MEMORY_SCOPE_AGENT);
        while (__hip_atomic_load(b, __ATOMIC_RELAXED, __HIP_MEMORY_SCOPE_AGENT) < nb)
            __builtin_amdgcn_s_sleep(2);
        __threadfence();   // acquire (inv)
    }
    __syncthreads();
}

// =====================================================================
// Split-precision MFMA GEMM (unchanged from round 4/5).
// =====================================================================
template<int BM, bool BIAS, bool TANH>
__global__ __launch_bounds__(256) void gemm_k(
    const float* __restrict__ A, int64_t lda, int64_t sA,
    const float* __restrict__ W, int64_t ldw, int64_t sW,
    float* __restrict__ C, int64_t ldc, int64_t sC,
    const float* __restrict__ bias, int64_t sBias,
    int K)
{
    constexpr int FM = BM / 32;
    __shared__ __align__(16) bf16 Ahi[BM * 32], Alo[BM * 32];
    __shared__ __align__(16) bf16 Whi[128 * 32], Wlo[128 * 32];
    const int z    = blockIdx.z;
    const float* Ab = A + (int64_t)z * sA;
    const float* Wb = W + (int64_t)z * sW;
    const int n0   = blockIdx.x * 128;
    const int m0   = blockIdx.y * BM;
    const int tid  = threadIdx.x;
    const int lane = tid & 63, wid = tid >> 6;
    const int wm   = wid >> 1, wn = wid & 1;
    const int srow = lane >> 2;
    const int skb  = (lane & 3) * 8;
    const int r16  = lane & 15;
    const int k8   = (lane >> 4) * 8;

    f32x4 acc[FM][4];
    #pragma unroll
    for (int i = 0; i < FM; i++)
        #pragma unroll
        for (int j = 0; j < 4; j++)
            acc[i][j] = f32x4{0.f, 0.f, 0.f, 0.f};

    for (int k0 = 0; k0 < K; k0 += 32) {
        for (int c = wid; c < BM / 16; c += 4) {
            bf16x8 h8, l8;
            split8(Ab + (int64_t)(m0 + c * 16 + srow) * lda + k0 + skb, h8, l8);
            *(bf16x8*)(Ahi + c * 512 + lane * 8) = h8;
            *(bf16x8*)(Alo + c * 512 + lane * 8) = l8;
        }
        for (int c = wid; c < 8; c += 4) {
            bf16x8 h8, l8;
            split8(Wb + (int64_t)(n0 + c * 16 + srow) * ldw + k0 + skb, h8, l8);
            *(bf16x8*)(Whi + c * 512 + lane * 8) = h8;
            *(bf16x8*)(Wlo + c * 512 + lane * 8) = l8;
        }
        __syncthreads();
        bf16x8 afh[FM], afl[FM], wfh[4], wfl[4];
        #pragma unroll
        for (int mt = 0; mt < FM; mt++) {
            const int off = (wm * (BM / 2) + mt * 16 + r16) * 32 + k8;
            afh[mt] = ld8(Ahi + off);
            afl[mt] = ld8(Alo + off);
        }
        #pragma unroll
        for (int nt = 0; nt < 4; nt++) {
            const int off = (wn * 64 + nt * 16 + r16) * 32 + k8;
            wfh[nt] = ld8(Whi + off);
            wfl[nt] = ld8(Wlo + off);
        }
        #pragma unroll
        for (int mt = 0; mt < FM; mt++)
            #pragma unroll
            for (int nt = 0; nt < 4; nt++)
                acc[mt][nt] = mfma3(afh[mt], afl[mt], wfh[nt], wfl[nt], acc[mt][nt]);
        __syncthreads();
    }
    #pragma unroll
    for (int nt = 0; nt < 4; nt++) {
        const int n = n0 + wn * 64 + nt * 16 + r16;
        float bv = 0.f;
        if constexpr (BIAS) bv = bias[(int64_t)z * sBias + n];
        #pragma unroll
        for (int mt = 0; mt < FM; mt++) {
            const int mb = m0 + wm * (BM / 2) + mt * 16 + (lane >> 4) * 4;
            #pragma unroll
            for (int r = 0; r < 4; r++) {
                float v = acc[mt][nt][r] + bv;
                if constexpr (TANH) v = tanhf(v);
                C[(int64_t)z * sC + (int64_t)(mb + r) * ldc + n] = v;
            }
        }
    }
}

__global__ void presplit_k(const float* __restrict__ x, bf16* __restrict__ hi,
                           bf16* __restrict__ lo, int n)
{
    const int i = blockIdx.x * 256 + threadIdx.x;
    if (i < n) {
        float v = x[i];
        bf16 h = f2b(v);
        hi[i] = h;
        lo[i] = f2b(v - b2f(h));
    }
}

__global__ void embed_k(const int* __restrict__ toks, const float* __restrict__ tab,
                        float* __restrict__ out, int shifted)
{
    const int row = blockIdx.x;
    int tok;
    if (shifted) {
        const int t = row / NB, b = row - t * NB;
        tok = (t == 0) ? SOST : toks[(t - 1) * NB + b];
    } else {
        tok = toks[row];
    }
    const uint4* s = (const uint4*)(tab + (int64_t)tok * HD);
    uint4* d = (uint4*)(out + (int64_t)row * HD);
    d[threadIdx.x] = s[threadIdx.x];
}

// =====================================================================
// Persistent encoder layer, W in registers.
// Grid (HHD/16=32 j-slices, 2 dirs) x 256 thr (4 waves, K-split 128/wave).
// Per wave: W frags wh/wl[3][4] = 96 VGPR. LDS reduce -> wave0 cell.
// =====================================================================
__global__ __launch_bounds__(256, 1) void enc_persist_k(
    const float* __restrict__ gi,     // [2][LI*NB][3*HHD] (+b_ih)
    const bf16* __restrict__ whhHi,
    const bf16* __restrict__ whhLo,
    const float* __restrict__ bhh,
    float* __restrict__ h32,          // [2 par][2 dir][NB][HHD]
    bf16* __restrict__ hHi, bf16* __restrict__ hLo,
    float* __restrict__ Y,
    float* __restrict__ dh32, bf16* __restrict__ dhHi, bf16* __restrict__ dhLo,
    int* __restrict__ bar)
{
    __shared__ f32x4 red[4][6][64];   // 24 KiB
    const int d = blockIdx.y;
    const int j0 = blockIdx.x * 16;
    const int tid = threadIdx.x;
    const int lane = tid & 63, wid = tid >> 6;
    const int r16 = lane & 15, k8 = (lane >> 4) * 8;
    const int kq = wid * 128;
    const bf16* WdH = whhHi + (int64_t)d * 3 * HHD * HHD;
    const bf16* WdL = whhLo + (int64_t)d * 3 * HHD * HHD;
    const int j = j0 + r16;

    // preload W fragments into registers (survive L2 invalidation)
    bf16x8 wh[3][4], wl[3][4];
    #pragma unroll
    for (int g = 0; g < 3; g++)
        #pragma unroll
        for (int kk = 0; kk < 4; kk++) {
            const int64_t wo = (int64_t)(g * HHD + j0 + r16) * HHD + kq + kk * 32 + k8;
            wh[g][kk] = ld8(WdH + wo);
            wl[g][kk] = ld8(WdL + wo);
        }
    const float br = bhh[d * 3 * HHD + j];
    const float bz = bhh[d * 3 * HHD + HHD + j];
    const float bn = bhh[d * 3 * HHD + 2 * HHD + j];

    for (int s = 0; s < LI; s++) {
        const int t = d ? (LI - 1 - s) : s;
        const int par = s & 1, npar = par ^ 1;
        const int64_t hbase = (int64_t)(par * 2 + d) * NB * HHD;

        f32x4 acc[2][3];
        #pragma unroll
        for (int m = 0; m < 2; m++)
            #pragma unroll
            for (int g = 0; g < 3; g++) acc[m][g] = f32x4{0.f, 0.f, 0.f, 0.f};

        #pragma unroll
        for (int kk = 0; kk < 4; kk++) {
            const int64_t o0 = hbase + (int64_t)r16 * HHD + kq + kk * 32 + k8;
            const int64_t o1 = hbase + (int64_t)(16 + r16) * HHD + kq + kk * 32 + k8;
            bf16x8 a0h = ld8(hHi + o0), a0l = ld8(hLo + o0);
            bf16x8 a1h = ld8(hHi + o1), a1l = ld8(hLo + o1);
            #pragma unroll
            for (int g = 0; g < 3; g++) {
                acc[0][g] = mfma3(a0h, a0l, wh[g][kk], wl[g][kk], acc[0][g]);
                acc[1][g] = mfma3(a1h, a1l, wh[g][kk], wl[g][kk], acc[1][g]);
            }
        }
        #pragma unroll
        for (int m = 0; m < 2; m++)
            #pragma unroll
            for (int g = 0; g < 3; g++)
                red[wid][m * 3 + g][lane] = acc[m][g];
        __syncthreads();
        if (wid == 0) {
            f32x4 a2[2][3];
            #pragma unroll
            for (int m = 0; m < 2; m++)
                #pragma unroll
                for (int g = 0; g < 3; g++)
                    a2[m][g] = red[0][m * 3 + g][lane] + red[1][m * 3 + g][lane]
                             + red[2][m * 3 + g][lane] + red[3][m * 3 + g][lane];
            const float* gid = gi + ((int64_t)d * LI * NB + (int64_t)t * NB) * (3 * HHD);
            #pragma unroll
            for (int mt = 0; mt < 2; mt++)
                #pragma unroll
                for (int r = 0; r < 4; r++) {
                    const int b = mt * 16 + (lane >> 4) * 4 + r;
                    const float ir  = gid[b * 3 * HHD + j];
                    const float iz  = gid[b * 3 * HHD + HHD + j];
                    const float inn = gid[b * 3 * HHD + 2 * HHD + j];
                    const float rg = sigm(ir + a2[mt][0][r] + br);
                    const float zg = sigm(iz + a2[mt][1][r] + bz);
                    const float ng = tanhf(inn + rg * (a2[mt][2][r] + bn));
                    const float hold = h32[hbase + (int64_t)b * HHD + j];
                    const float hnew = (1.f - zg) * ng + zg * hold;
                    const int64_t no = (int64_t)(npar * 2 + d) * NB * HHD + (int64_t)b * HHD + j;
                    bf16 hh = f2b(hnew);
                    h32[no] = hnew;
                    hHi[no] = hh;
                    hLo[no] = f2b(hnew - b2f(hh));
                    Y[((int64_t)t * NB + b) * HD + d * HHD + j] = hnew;
                    if (s == LI - 1) {
                        const int64_t dof = (int64_t)b * HD + d * HHD + j;
                        dh32[dof] = hnew;
                        dhHi[dof] = hh;
                        dhLo[dof] = f2b(hnew - b2f(hh));
                    }
                }
        }
        if (s < LI - 1) gbar(&bar[s], 64);
    }
}

// =====================================================================
// Persistent decoder, W in registers. Grid (HD/16=64, 3) x 512 thr (8 waves).
//  y==0: layer0, in-block K-split 128/wave (W 96 VGPR).
//  y==1,2: layer1 K-half kh=y-1; per wave K-slice 64 of wih1+whh1 (96 VGPR).
//          Cross-pair reduce via PART scratch + 2nd barrier; kh==0 does cell.
// 2 barriers/iteration, 65 iterations.
// =====================================================================
__global__ __launch_bounds__(512, 1) void dec_persist_k(
    const float* __restrict__ gi0,
    const bf16* __restrict__ wih1Hi, const bf16* __restrict__ wih1Lo,
    const bf16* __restrict__ whh0Hi, const bf16* __restrict__ whh0Lo,
    const bf16* __restrict__ whh1Hi, const bf16* __restrict__ whh1Lo,
    const float* __restrict__ bih1,
    const float* __restrict__ bhh0,
    const float* __restrict__ bhh1,
    float* __restrict__ h32,          // [2 par][NLAY][NB][HD]
    bf16* __restrict__ hHi, bf16* __restrict__ hLo,
    float* __restrict__ rnn,
    f32x4* __restrict__ part,         // [64 j][8 grp][64 lane]
    int* __restrict__ bar)            // 2 per iteration
{
    __shared__ f32x4 red[8][8][64];   // 64 KiB
    const int tid = threadIdx.x;
    const int lane = tid & 63, wid = tid >> 6;
    const int r16 = lane & 15, k8 = (lane >> 4) * 8;
    const int j0 = blockIdx.x * 16;
    const int j = j0 + r16;
    const int NBLK = 64 * 3;

    if (blockIdx.y == 0) {
        // ---- layer 0 ----
        const int kq = wid * 128;
        bf16x8 wh[3][4], wl[3][4];
        #pragma unroll
        for (int g = 0; g < 3; g++)
            #pragma unroll
            for (int kk = 0; kk < 4; kk++) {
                const int64_t wo = (int64_t)(g * HD + j0 + r16) * HD + kq + kk * 32 + k8;
                wh[g][kk] = ld8(whh0Hi + wo);
                wl[g][kk] = ld8(whh0Lo + wo);
            }
        const float b0r = bhh0[j], b0z = bhh0[HD + j], b0n = bhh0[2 * HD + j];

        for (int s = 0; s <= LO; s++) {
            if (s < LO) {
                const int t = s, par = t & 1, npar = par ^ 1;
                const int64_t hb = (int64_t)(par * NLAY + 0) * NB * HD;
                f32x4 acc[2][3];
                #pragma unroll
                for (int m = 0; m < 2; m++)
                    #pragma unroll
                    for (int g = 0; g < 3; g++) acc[m][g] = f32x4{0.f, 0.f, 0.f, 0.f};
                #pragma unroll
                for (int kk = 0; kk < 4; kk++) {
                    const int64_t o0 = hb + (int64_t)r16 * HD + kq + kk * 32 + k8;
                    const int64_t o1 = hb + (int64_t)(16 + r16) * HD + kq + kk * 32 + k8;
                    bf16x8 a0h = ld8(hHi + o0), a0l = ld8(hLo + o0);
                    bf16x8 a1h = ld8(hHi + o1), a1l = ld8(hLo + o1);
                    #pragma unroll
                    for (int g = 0; g < 3; g++) {
                        acc[0][g] = mfma3(a0h, a0l, wh[g][kk], wl[g][kk], acc[0][g]);
                        acc[1][g] = mfma3(a1h, a1l, wh[g][kk], wl[g][kk], acc[1][g]);
                    }
                }
                #pragma unroll
                for (int m = 0; m < 2; m++)
                    #pragma unroll
                    for (int g = 0; g < 3; g++)
                        red[wid][m * 3 + g][lane] = acc[m][g];
                __syncthreads();
                if (wid == 0) {
                    f32x4 a2[2][3];
                    #pragma unroll
                    for (int m = 0; m < 2; m++)
                        #pragma unroll
                        for (int g = 0; g < 3; g++) {
                            f32x4 v = red[0][m * 3 + g][lane];
                            #pragma unroll
                            for (int w2 = 1; w2 < 8; w2++) v += red[w2][m * 3 + g][lane];
                            a2[m][g] = v;
                        }
                    const float* gid = gi0 + (int64_t)t * NB * 3 * HD;
                    #pragma unroll
                    for (int mt = 0; mt < 2; mt++)
                        #pragma unroll
                        for (int r = 0; r < 4; r++) {
                            const int b = mt * 16 + (lane >> 4) * 4 + r;
                            const float ir  = gid[b * 3 * HD + j];
                            const float iz  = gid[b * 3 * HD + HD + j];
                            const float inn = gid[b * 3 * HD + 2 * HD + j];
                            const float rg = sigm(ir + a2[mt][0][r] + b0r);
                            const float zg = sigm(iz + a2[mt][1][r] + b0z);
                            const float ng = tanhf(inn + rg * (a2[mt][2][r] + b0n));
                            const float hold = h32[hb + (int64_t)b * HD + j];
                            const float hnew = (1.f - zg) * ng + zg * hold;
                            const int64_t no = (int64_t)(npar * NLAY + 0) * NB * HD + (int64_t)b * HD + j;
                            bf16 hh = f2b(hnew);
                            h32[no] = hnew;
                            hHi[no] = hh;
                            hLo[no] = f2b(hnew - b2f(hh));
                        }
                }
            }
            gbar(&bar[2 * s], NBLK);
            if (s < LO) gbar(&bar[2 * s + 1], NBLK);
        }
    } else {
        // ---- layer 1, K-half kh ----
        const int kh = blockIdx.y - 1;
        const int kb = kh * 512 + wid * 64;
        bf16x8 wIh[3][2], wIl[3][2], wHh[3][2], wHl[3][2];
        #pragma unroll
        for (int g = 0; g < 3; g++)
            #pragma unroll
            for (int kk = 0; kk < 2; kk++) {
                const int64_t wo = (int64_t)(g * HD + j0 + r16) * HD + kb + kk * 32 + k8;
                wIh[g][kk] = ld8(wih1Hi + wo);
                wIl[g][kk] = ld8(wih1Lo + wo);
                wHh[g][kk] = ld8(whh1Hi + wo);
                wHl[g][kk] = ld8(whh1Lo + wo);
            }
        const float brr = bih1[j] + bhh1[j];
        const float bzz = bih1[HD + j] + bhh1[HD + j];
        const float bin = bih1[2 * HD + j];
        const float bhn = bhh1[2 * HD + j];

        for (int s = 0; s <= LO; s++) {
            f32x4 p[8];
            if (s >= 1) {
                const int t = s - 1;
                const int p0 = (t + 1) & 1;
                const int p1 = t & 1;
                const int64_t h0b = (int64_t)(p0 * NLAY + 0) * NB * HD;
                const int64_t h1b = (int64_t)(p1 * NLAY + 1) * NB * HD;
                f32x4 arz[2][2], ain[2], ahn[2];
                #pragma unroll
                for (int i = 0; i < 2; i++) {
                    arz[i][0] = f32x4{0.f, 0.f, 0.f, 0.f};
                    arz[i][1] = f32x4{0.f, 0.f, 0.f, 0.f};
                    ain[i] = f32x4{0.f, 0.f, 0.f, 0.f};
                    ahn[i] = f32x4{0.f, 0.f, 0.f, 0.f};
                }
                #pragma unroll
                for (int kk = 0; kk < 2; kk++) {
                    const int64_t xo0 = h0b + (int64_t)r16 * HD + kb + kk * 32 + k8;
                    const int64_t xo1 = h0b + (int64_t)(16 + r16) * HD + kb + kk * 32 + k8;
                    const int64_t yo0 = h1b + (int64_t)r16 * HD + kb + kk * 32 + k8;
                    const int64_t yo1 = h1b + (int64_t)(16 + r16) * HD + kb + kk * 32 + k8;
                    bf16x8 x0h = ld8(hHi + xo0), x0l = ld8(hLo + xo0);
                    bf16x8 x1h = ld8(hHi + xo1), x1l = ld8(hLo + xo1);
                    bf16x8 y0h = ld8(hHi + yo0), y0l = ld8(hLo + yo0);
                    bf16x8 y1h = ld8(hHi + yo1), y1l = ld8(hLo + yo1);
                    arz[0][0] = mfma3(x0h, x0l, wIh[0][kk], wIl[0][kk], arz[0][0]);
                    arz[0][0] = mfma3(y0h, y0l, wHh[0][kk], wHl[0][kk], arz[0][0]);
                    arz[1][0] = mfma3(x1h, x1l, wIh[0][kk], wIl[0][kk], arz[1][0]);
                    arz[1][0] = mfma3(y1h, y1l, wHh[0][kk], wHl[0][kk], arz[1][0]);
                    arz[0][1] = mfma3(x0h, x0l, wIh[1][kk], wIl[1][kk], arz[0][1]);
                    arz[0][1] = mfma3(y0h, y0l, wHh[1][kk], wHl[1][kk], arz[0][1]);
                    arz[1][1] = mfma3(x1h, x1l, wIh[1][kk], wIl[1][kk], arz[1][1]);
                    arz[1][1] = mfma3(y1h, y1l, wHh[1][kk], wHl[1][kk], arz[1][1]);
                    ain[0] = mfma3(x0h, x0l, wIh[2][kk], wIl[2][kk], ain[0]);
                    ain[1] = mfma3(x1h, x1l, wIh[2][kk], wIl[2][kk], ain[1]);
                    ahn[0] = mfma3(y0h, y0l, wHh[2][kk], wHl[2][kk], ahn[0]);
                    ahn[1] = mfma3(y1h, y1l, wHh[2][kk], wHl[2][kk], ahn[1]);
                }
                red[wid][0][lane] = arz[0][0];
                red[wid][1][lane] = arz[1][0];
                red[wid][2][lane] = arz[0][1];
                red[wid][3][lane] = arz[1][1];
                red[wid][4][lane] = ain[0];
                red[wid][5][lane] = ain[1];
                red[wid][6][lane] = ahn[0];
                red[wid][7][lane] = ahn[1];
                __syncthreads();
                if (wid == 0) {
                    #pragma unroll
                    for (int grp = 0; grp < 8; grp++) {
                        f32x4 v = red[0][grp][lane];
                        #pragma unroll
                        for (int w2 = 1; w2 < 8; w2++) v += red[w2][grp][lane];
                        p[grp] = v;
                    }
                    if (kh == 1) {
                        #pragma unroll
                        for (int grp = 0; grp < 8; grp++)
                            part[((size_t)blockIdx.x * 8 + grp) * 64 + lane] = p[grp];
                    }
                }
            }
            gbar(&bar[2 * s], NBLK);
            if (s >= 1 && kh == 0 && wid == 0) {
                const int t = s - 1;
                const int p1 = t & 1, np1 = p1 ^ 1;
                const int64_t h1b = (int64_t)(p1 * NLAY + 1) * NB * HD;
                #pragma unroll
                for (int grp = 0; grp < 8; grp++)
                    p[grp] += part[((size_t)blockIdx.x * 8 + grp) * 64 + lane];
                #pragma unroll
                for (int mt = 0; mt < 2; mt++)
                    #pragma unroll
                    for (int r = 0; r < 4; r++) {
                        const int b = mt * 16 + (lane >> 4) * 4 + r;
                        const float rg = sigm(p[0 + mt][r] + brr);          // arz[mt][0]
                        const float zg = sigm(p[2 + mt][r] + bzz);          // arz[mt][1]
                        const float ng = tanhf(p[4 + mt][r] + bin + rg * (p[6 + mt][r] + bhn));
                        const float hold = h32[h1b + (int64_t)b * HD + j];
                        const float hnew = (1.f - zg) * ng + zg * hold;
                        const int64_t no = (int64_t)(np1 * NLAY + 1) * NB * HD + (int64_t)b * HD + j;
                        bf16 hh = f2b(hnew);
                        h32[no] = hnew;
                        hHi[no] = hh;
                        hLo[no] = f2b(hnew - b2f(hh));
                        rnn[((int64_t)t * NB + b) * HD + j] = hnew;
                    }
            }
            if (s < LO) gbar(&bar[2 * s + 1], NBLK);
        }
    }
}

// =====================================================================
__global__ __launch_bounds__(64) void softmax_k(const float* __restrict__ sc,
                                                float* __restrict__ aout)
{
    const int row = blockIdx.x, l = threadIdx.x;
    float v0 = sc[row * LI + l], v1 = sc[row * LI + 64 + l];
    float m = fmaxf(v0, v1);
    #pragma unroll
    for (int o = 32; o > 0; o >>= 1) m = fmaxf(m, __shfl_xor(m, o));
    float e0 = expf(v0 - m), e1 = expf(v1 - m);
    float s = e0 + e1;
    #pragma unroll
    for (int o = 32; o > 0; o >>= 1) s += __shfl_xor(s, o);
    const float inv = 1.f / s;
    aout[row * LI + l] = e0 * inv;
    aout[row * LI + 64 + l] = e1 * inv;
}

__global__ __launch_bounds__(256) void ctx_k(const float* __restrict__ at,
                                             const float* __restrict__ enc,
                                             float* __restrict__ jin)
{
    const int b = blockIdx.y, h0 = blockIdx.x * 128;
    __shared__ __align__(16) float al[LO][LI];
    for (int i = threadIdx.x; i < LO * LI; i += 256) {
        const int to = i >> 7, ti = i & 127;
        al[to][ti] = at[(to * NB + b) * LI + ti];
    }
    __syncthreads();
    const int hc = h0 + (threadIdx.x & 127);
    const int rh = threadIdx.x >> 7;
    float acc[32];
    #pragma unroll
    for (int i = 0; i < 32; i++) acc[i] = 0.f;
    for (int t = 0; t < LI; t++) {
        const float ev = enc[((int64_t)t * NB + b) * HD + hc];
        #pragma unroll
        for (int i = 0; i < 32; i++) acc[i] += ev * al[rh * 32 + i][t];
    }
    #pragma unroll
    for (int i = 0; i < 32; i++)
        jin[((int64_t)(rh * 32 + i) * NB + b) * (2 * HD) + hc] = acc[i];
}

__global__ void rnncopy_k(const float* __restrict__ rnn, float* __restrict__ jin)
{
    const int idx = blockIdx.x * 256 + threadIdx.x;
    const int row = idx >> 8;
    const int c = idx & 255;
    ((uint4*)jin)[(int64_t)row * 512 + 256 + c] = ((const uint4*)rnn)[idx];
}

// =====================================================================
extern "C" void kernel_launch(void* const* d_in, const int* in_sizes, int n_in,
                              void* d_out, int out_size, void* d_ws, size_t ws_size,
                              hipStream_t stream)
{
    (void)in_sizes; (void)n_in; (void)out_size; (void)ws_size;
    const int*   in_tok   = (const int*)d_in[0];
    const int*   out_tok  = (const int*)d_in[2];
    const float* enc_emb  = (const float*)d_in[4];
    const float* enc_wih  = (const float*)d_in[5];
    const float* enc_whh  = (const float*)d_in[6];
    const float* enc_bih  = (const float*)d_in[7];
    const float* enc_bhh  = (const float*)d_in[8];
    const float* dec_emb  = (const float*)d_in[9];
    const float* dec_wih  = (const float*)d_in[10];
    const float* dec_whh  = (const float*)d_in[11];
    const float* dec_bih  = (const float*)d_in[12];
    const float* dec_bhh  = (const float*)d_in[13];
    const float* attn_W   = (const float*)d_in[14];
    const float* joiner_W = (const float*)d_in[15];
    const float* joiner_b = (const float*)d_in[16];
    const float* proj_W   = (const float*)d_in[17];
    const float* proj_b   = (const float*)d_in[18];
    float* logits   = (float*)d_out;
    float* attn_out = logits + (size_t)LO * NB * NV;

    const size_t MB = 1ull << 20;
    char* o = (char*)d_out;
    float* XB0   = (float*)(o);              // 16 MiB enc embedded input
    float* XB1   = (float*)(o + 16 * MB);    // 16 MiB enc layer0 output
    float* EOUT  = (float*)(o + 32 * MB);    // 16 MiB enc_outputs
    float* PENC  = (float*)(o + 48 * MB);    // 16 MiB proj_enc
    float* GI    = (float*)(o + 64 * MB);    // 48 MiB enc gi (both dirs)
    float* DEMB  = (float*)(o + 112 * MB);   //  8 MiB dec embedded
    float* DGI0  = (float*)(o + 120 * MB);   // 24 MiB dec layer0 gi
    float* RNN   = (float*)(o + 144 * MB);   //  8 MiB rnn_out
    float* SC    = (float*)(o + 152 * MB);   //  1 MiB scores
    float* JIN   = (float*)(o + 153 * MB);   // 16 MiB cat(ctx, rnn)
    bf16* WencHi = (bf16*)(o + 169 * MB);    //  6 MiB enc_whh hi
    bf16* WencLo = (bf16*)(o + 175 * MB);    //  6 MiB enc_whh lo
    bf16* WdhHi  = (bf16*)(o + 181 * MB);    // 12 MiB dec_whh hi
    bf16* WdhLo  = (bf16*)(o + 193 * MB);    // 12 MiB dec_whh lo
    bf16* Wih1Hi = (bf16*)(o + 205 * MB);    //  6 MiB dec_wih[1] hi
    bf16* Wih1Lo = (bf16*)(o + 211 * MB);    //  6 MiB dec_wih[1] lo
    int*  BAR_E0 = (int*)(o + 218 * MB);     // 128 ints
    int*  BAR_E1 = BAR_E0 + 128;             // 128 ints
    int*  BAR_D  = BAR_E0 + 256;             // 132 ints
    f32x4* PART  = (f32x4*)(o + 219 * MB);   // 512 KiB layer1 partials

    char* w = (char*)d_ws;                   // 10 MiB total
    float* VECS = (float*)(w);                       // 8 MiB tanh(joiner)
    float* EH32 = (float*)(w + 8 * MB);              // 512 KiB
    bf16*  EHhi = (bf16*) (w + 8 * MB + 524288);     // 256 KiB
    bf16*  EHlo = (bf16*) (w + 8 * MB + 786432);     // 256 KiB
    float* DH32 = (float*)(w + 9 * MB);              // 512 KiB
    bf16*  DHhi = (bf16*) (w + 9 * MB + 524288);     // 256 KiB
    bf16*  DHlo = (bf16*) (w + 9 * MB + 786432);     // 256 KiB

    hipMemsetAsync(BAR_E0, 0, (256 + 132) * sizeof(int), stream);

    // ---- pre-split recurrent weights ----
    const int nEnc = NLAY * 2 * 3 * HHD * HHD;
    const int nDhh = NLAY * 3 * HD * HD;
    const int nIh1 = 3 * HD * HD;
    presplit_k<<<dim3((nEnc + 255) / 256), dim3(256), 0, stream>>>(enc_whh, WencHi, WencLo, nEnc);
    presplit_k<<<dim3((nDhh + 255) / 256), dim3(256), 0, stream>>>(dec_whh, WdhHi, WdhLo, nDhh);
    presplit_k<<<dim3((nIh1 + 255) / 256), dim3(256), 0, stream>>>(dec_wih + (size_t)3 * HD * HD, Wih1Hi, Wih1Lo, nIh1);

    // ---- decoder prep ----
    embed_k<<<dim3(LO * NB), dim3(256), 0, stream>>>(out_tok, dec_emb, DEMB, 1);
    gemm_k<128, true, false><<<dim3(3 * HD / 128, LO * NB / 128, 1), 256, 0, stream>>>(
        DEMB, HD, 0, dec_wih, HD, 0, DGI0, 3 * HD, 0, dec_bih, 0, HD);

    // ---- encoder ----
    embed_k<<<dim3(LI * NB), dim3(256), 0, stream>>>(in_tok, enc_emb, XB0, 0);
    for (int l = 0; l < NLAY; l++) {
        const float* Xin = l ? XB1 : XB0;
        float* Yout = l ? EOUT : XB1;
        hipMemsetAsync(EH32, 0, (size_t)2 * 2 * NB * HHD * 4, stream);
        hipMemsetAsync(EHhi, 0, (size_t)2 * 2 * NB * HHD * 2, stream);
        hipMemsetAsync(EHlo, 0, (size_t)2 * 2 * NB * HHD * 2, stream);
        gemm_k<128, true, false><<<dim3(3 * HHD / 128, LI * NB / 128, 2), 256, 0, stream>>>(
            Xin, HD, 0,
            enc_wih + (size_t)l * 2 * 3 * HHD * HD, HD, (int64_t)3 * HHD * HD,
            GI, 3 * HHD, (int64_t)LI * NB * 3 * HHD,
            enc_bih + l * 2 * 3 * HHD, 3 * HHD, HD);
        enc_persist_k<<<dim3(HHD / 16, 2), dim3(256), 0, stream>>>(
            GI,
            WencHi + (size_t)l * 2 * 3 * HHD * HHD,
            WencLo + (size_t)l * 2 * 3 * HHD * HHD,
            enc_bhh + l * 2 * 3 * HHD,
            EH32, EHhi, EHlo, Yout,
            DH32 + (size_t)l * NB * HD, DHhi + (size_t)l * NB * HD,
            DHlo + (size_t)l * NB * HD,
            l ? BAR_E1 : BAR_E0);
    }

    // proj_enc = enc_outputs @ attn_W^T
    gemm_k<128, false, false><<<dim3(HD / 128, LI * NB / 128, 1), 256, 0, stream>>>(
        EOUT, HD, 0, attn_W, HD, 0, PENC, HD, 0, nullptr, 0, HD);

    // ---- decoder recurrence (persistent, W-in-regs) ----
    dec_persist_k<<<dim3(HD / 16, 3), dim3(512), 0, stream>>>(
        DGI0,
        Wih1Hi, Wih1Lo,
        WdhHi, WdhLo,
        WdhHi + (size_t)3 * HD * HD, WdhLo + (size_t)3 * HD * HD,
        dec_bih + 3 * HD, dec_bhh, dec_bhh + 3 * HD,
        DH32, DHhi, DHlo, RNN, PART, BAR_D);

    // ---- batched epilogue ----
    gemm_k<64, false, false><<<dim3(1, 1, NB), 256, 0, stream>>>(
        RNN, (int64_t)NB * HD, HD, PENC, (int64_t)NB * HD, HD,
        SC, (int64_t)NB * LI, LI, nullptr, 0, HD);
    softmax_k<<<dim3(LO * NB), dim3(64), 0, stream>>>(SC, attn_out);
    ctx_k<<<dim3(HD / 128, NB), dim3(256), 0, stream>>>(attn_out, EOUT, JIN);
    rnncopy_k<<<dim3(LO * NB * HD / 4 / 256), dim3(256), 0, stream>>>(RNN, JIN);
    gemm_k<128, true, true><<<dim3(HD / 128, LO * NB / 128, 1), 256, 0, stream>>>(
        JIN, 2 * HD, 0, joiner_W, 2 * HD, 0, VECS, HD, 0, joiner_b, 0, 2 * HD);
    gemm_k<128, true, false><<<dim3(NV / 128, LO * NB / 128, 1), 256, 0, stream>>>(
        VECS, HD, 0, proj_W, HD, 0, logits, NV, 0, proj_b, 0, HD);
}

// Round 7
// 6102.813 us; speedup vs baseline: 1.7329x; 1.2606x over previous
//
#include <hip/hip_runtime.h>
#include <hip/hip_bf16.h>
#include <stdint.h>

// ---- problem constants ----
constexpr int LI   = 128;    // L_IN
constexpr int LO   = 64;     // L_OUT
constexpr int NB   = 32;     // batch
constexpr int HD   = 1024;   // H
constexpr int HHD  = 512;    // HH
constexpr int NLAY = 2;
constexpr int NV   = 32000;  // V_OUT
constexpr int SOST = 1;

// All float tensors are FP32. Compute uses bf16x3 split MFMA (~fp32 precision).
// Persistent recurrence: W in registers; cross-block h-state exchanged via
// agent-scope (L3-coherent) atomics -> grid barrier needs NO threadfence
// (round-6 counters showed the fence's L2 wbl2/inv cost ~44us/step).

typedef __hip_bfloat16 bf16;
typedef __attribute__((ext_vector_type(8))) short bf16x8;
typedef __attribute__((ext_vector_type(4))) float f32x4;
typedef unsigned long long u64;

__device__ __forceinline__ float b2f(bf16 x) { return __bfloat162float(x); }
__device__ __forceinline__ bf16  f2b(float x) { return __float2bfloat16(x); }
__device__ __forceinline__ float sigm(float x) { return 1.0f / (1.0f + expf(-x)); }

__device__ __forceinline__ f32x4 mfma(bf16x8 a, bf16x8 b, f32x4 c) {
    return __builtin_amdgcn_mfma_f32_16x16x32_bf16(a, b, c, 0, 0, 0);
}
__device__ __forceinline__ f32x4 mfma3(bf16x8 ah, bf16x8 al, bf16x8 bh, bf16x8 bl, f32x4 c) {
    c = mfma(ah, bh, c);
    c = mfma(ah, bl, c);
    c = mfma(al, bh, c);
    return c;
}
__device__ __forceinline__ bf16x8 ld8(const bf16* p) { return *(const bf16x8*)p; }

// ---- coherent (agent/L3) exchange helpers ----
__device__ __forceinline__ bf16x8 ldc(const bf16* p) {   // 16B as 2x8B atomic
    union { bf16x8 v; u64 q[2]; } u;
    u.q[0] = __hip_atomic_load((const u64*)p,     __ATOMIC_RELAXED, __HIP_MEMORY_SCOPE_AGENT);
    u.q[1] = __hip_atomic_load((const u64*)p + 1, __ATOMIC_RELAXED, __HIP_MEMORY_SCOPE_AGENT);
    return u.v;
}
__device__ __forceinline__ void stc2(bf16* p, bf16 a, bf16 b) {  // 2 bf16 -> 4B atomic
    unsigned v = (unsigned)*(const unsigned short*)&a |
                 ((unsigned)*(const unsigned short*)&b << 16);
    __hip_atomic_store((unsigned*)p, v, __ATOMIC_RELAXED, __HIP_MEMORY_SCOPE_AGENT);
}
__device__ __forceinline__ f32x4 ldc4f(const float* p) {
    union { f32x4 v; u64 q[2]; } u;
    u.q[0] = __hip_atomic_load((const u64*)p,     __ATOMIC_RELAXED, __HIP_MEMORY_SCOPE_AGENT);
    u.q[1] = __hip_atomic_load((const u64*)p + 1, __ATOMIC_RELAXED, __HIP_MEMORY_SCOPE_AGENT);
    return u.v;
}
__device__ __forceinline__ void stc4f(float* p, f32x4 v) {
    union { f32x4 v; u64 q[2]; } u;
    u.v = v;
    __hip_atomic_store((u64*)p,     u.q[0], __ATOMIC_RELAXED, __HIP_MEMORY_SCOPE_AGENT);
    __hip_atomic_store((u64*)p + 1, u.q[1], __ATOMIC_RELAXED, __HIP_MEMORY_SCOPE_AGENT);
}

__device__ __forceinline__ void split8(const float* p, bf16x8& h8, bf16x8& l8) {
    #pragma unroll
    for (int j = 0; j < 8; j++) {
        float v = p[j];
        bf16 h = f2b(v);
        bf16 l = f2b(v - b2f(h));
        ((bf16*)&h8)[j] = h;
        ((bf16*)&l8)[j] = l;
    }
}

// ---- fence-free grid barrier: coherent data already at L3; just drain
// this wave's stores, bump counter, spin. Trailing __syncthreads is the
// compiler/exec fence for the block.
__device__ __forceinline__ void gbar(int* b, int nb) {
    __syncthreads();
    if (threadIdx.x == 0) {
        asm volatile("s_waitcnt vmcnt(0)" ::: "memory");
        __hip_atomic_fetch_add(b, 1, __ATOMIC_RELAXED, __HIP_MEMORY_SCOPE_AGENT);
        while (__hip_atomic_load(b, __ATOMIC_RELAXED, __HIP_MEMORY_SCOPE_AGENT) < nb)
            __builtin_amdgcn_s_sleep(1);
    }
    __syncthreads();
}

// =====================================================================
// Split-precision MFMA GEMM (unchanged).
// =====================================================================
template<int BM, bool BIAS, bool TANH>
__global__ __launch_bounds__(256) void gemm_k(
    const float* __restrict__ A, int64_t lda, int64_t sA,
    const float* __restrict__ W, int64_t ldw, int64_t sW,
    float* __restrict__ C, int64_t ldc, int64_t sC,
    const float* __restrict__ bias, int64_t sBias,
    int K)
{
    constexpr int FM = BM / 32;
    __shared__ __align__(16) bf16 Ahi[BM * 32], Alo[BM * 32];
    __shared__ __align__(16) bf16 Whi[128 * 32], Wlo[128 * 32];
    const int z    = blockIdx.z;
    const float* Ab = A + (int64_t)z * sA;
    const float* Wb = W + (int64_t)z * sW;
    const int n0   = blockIdx.x * 128;
    const int m0   = blockIdx.y * BM;
    const int tid  = threadIdx.x;
    const int lane = tid & 63, wid = tid >> 6;
    const int wm   = wid >> 1, wn = wid & 1;
    const int srow = lane >> 2;
    const int skb  = (lane & 3) * 8;
    const int r16  = lane & 15;
    const int k8   = (lane >> 4) * 8;

    f32x4 acc[FM][4];
    #pragma unroll
    for (int i = 0; i < FM; i++)
        #pragma unroll
        for (int j = 0; j < 4; j++)
            acc[i][j] = f32x4{0.f, 0.f, 0.f, 0.f};

    for (int k0 = 0; k0 < K; k0 += 32) {
        for (int c = wid; c < BM / 16; c += 4) {
            bf16x8 h8, l8;
            split8(Ab + (int64_t)(m0 + c * 16 + srow) * lda + k0 + skb, h8, l8);
            *(bf16x8*)(Ahi + c * 512 + lane * 8) = h8;
            *(bf16x8*)(Alo + c * 512 + lane * 8) = l8;
        }
        for (int c = wid; c < 8; c += 4) {
            bf16x8 h8, l8;
            split8(Wb + (int64_t)(n0 + c * 16 + srow) * ldw + k0 + skb, h8, l8);
            *(bf16x8*)(Whi + c * 512 + lane * 8) = h8;
            *(bf16x8*)(Wlo + c * 512 + lane * 8) = l8;
        }
        __syncthreads();
        bf16x8 afh[FM], afl[FM], wfh[4], wfl[4];
        #pragma unroll
        for (int mt = 0; mt < FM; mt++) {
            const int off = (wm * (BM / 2) + mt * 16 + r16) * 32 + k8;
            afh[mt] = ld8(Ahi + off);
            afl[mt] = ld8(Alo + off);
        }
        #pragma unroll
        for (int nt = 0; nt < 4; nt++) {
            const int off = (wn * 64 + nt * 16 + r16) * 32 + k8;
            wfh[nt] = ld8(Whi + off);
            wfl[nt] = ld8(Wlo + off);
        }
        #pragma unroll
        for (int mt = 0; mt < FM; mt++)
            #pragma unroll
            for (int nt = 0; nt < 4; nt++)
                acc[mt][nt] = mfma3(afh[mt], afl[mt], wfh[nt], wfl[nt], acc[mt][nt]);
        __syncthreads();
    }
    #pragma unroll
    for (int nt = 0; nt < 4; nt++) {
        const int n = n0 + wn * 64 + nt * 16 + r16;
        float bv = 0.f;
        if constexpr (BIAS) bv = bias[(int64_t)z * sBias + n];
        #pragma unroll
        for (int mt = 0; mt < FM; mt++) {
            const int mb = m0 + wm * (BM / 2) + mt * 16 + (lane >> 4) * 4;
            #pragma unroll
            for (int r = 0; r < 4; r++) {
                float v = acc[mt][nt][r] + bv;
                if constexpr (TANH) v = tanhf(v);
                C[(int64_t)z * sC + (int64_t)(mb + r) * ldc + n] = v;
            }
        }
    }
}

__global__ void presplit_k(const float* __restrict__ x, bf16* __restrict__ hi,
                           bf16* __restrict__ lo, int n)
{
    const int i = blockIdx.x * 256 + threadIdx.x;
    if (i < n) {
        float v = x[i];
        bf16 h = f2b(v);
        hi[i] = h;
        lo[i] = f2b(v - b2f(h));
    }
}

__global__ void embed_k(const int* __restrict__ toks, const float* __restrict__ tab,
                        float* __restrict__ out, int shifted)
{
    const int row = blockIdx.x;
    int tok;
    if (shifted) {
        const int t = row / NB, b = row - t * NB;
        tok = (t == 0) ? SOST : toks[(t - 1) * NB + b];
    } else {
        tok = toks[row];
    }
    const uint4* s = (const uint4*)(tab + (int64_t)tok * HD);
    uint4* d = (uint4*)(out + (int64_t)row * HD);
    d[threadIdx.x] = s[threadIdx.x];
}

// =====================================================================
// Persistent encoder layer, W in registers, coherent h exchange.
// Grid (HHD/16=32, 2 dirs) x 256 thr (4 waves, K-split 128/wave).
// =====================================================================
__global__ __launch_bounds__(256, 1) void enc_persist_k(
    const float* __restrict__ gi,
    const bf16* __restrict__ whhHi,
    const bf16* __restrict__ whhLo,
    const float* __restrict__ bhh,
    float* __restrict__ h32,          // [2 par][2 dir][NB][HHD] (block-private slice)
    bf16* __restrict__ hHi, bf16* __restrict__ hLo,   // coherent exchange
    float* __restrict__ Y,
    float* __restrict__ dh32, bf16* __restrict__ dhHi, bf16* __restrict__ dhLo,
    int* __restrict__ bar)
{
    __shared__ f32x4 red[4][6][64];   // 24 KiB
    const int d = blockIdx.y;
    const int j0 = blockIdx.x * 16;
    const int tid = threadIdx.x;
    const int lane = tid & 63, wid = tid >> 6;
    const int r16 = lane & 15, k8 = (lane >> 4) * 8;
    const int kq = wid * 128;
    const bf16* WdH = whhHi + (int64_t)d * 3 * HHD * HHD;
    const bf16* WdL = whhLo + (int64_t)d * 3 * HHD * HHD;
    const int j = j0 + r16;

    bf16x8 wh[3][4], wl[3][4];
    #pragma unroll
    for (int g = 0; g < 3; g++)
        #pragma unroll
        for (int kk = 0; kk < 4; kk++) {
            const int64_t wo = (int64_t)(g * HHD + j0 + r16) * HHD + kq + kk * 32 + k8;
            wh[g][kk] = ld8(WdH + wo);
            wl[g][kk] = ld8(WdL + wo);
        }
    const float br = bhh[d * 3 * HHD + j];
    const float bz = bhh[d * 3 * HHD + HHD + j];
    const float bn = bhh[d * 3 * HHD + 2 * HHD + j];

    for (int s = 0; s < LI; s++) {
        const int t = d ? (LI - 1 - s) : s;
        const int par = s & 1, npar = par ^ 1;
        const int64_t hbase = (int64_t)(par * 2 + d) * NB * HHD;

        f32x4 acc[2][3];
        #pragma unroll
        for (int m = 0; m < 2; m++)
            #pragma unroll
            for (int g = 0; g < 3; g++) acc[m][g] = f32x4{0.f, 0.f, 0.f, 0.f};

        #pragma unroll
        for (int kk = 0; kk < 4; kk++) {
            const int64_t o0 = hbase + (int64_t)r16 * HHD + kq + kk * 32 + k8;
            const int64_t o1 = hbase + (int64_t)(16 + r16) * HHD + kq + kk * 32 + k8;
            bf16x8 a0h = ldc(hHi + o0), a0l = ldc(hLo + o0);
            bf16x8 a1h = ldc(hHi + o1), a1l = ldc(hLo + o1);
            #pragma unroll
            for (int g = 0; g < 3; g++) {
                acc[0][g] = mfma3(a0h, a0l, wh[g][kk], wl[g][kk], acc[0][g]);
                acc[1][g] = mfma3(a1h, a1l, wh[g][kk], wl[g][kk], acc[1][g]);
            }
        }
        #pragma unroll
        for (int m = 0; m < 2; m++)
            #pragma unroll
            for (int g = 0; g < 3; g++)
                red[wid][m * 3 + g][lane] = acc[m][g];
        __syncthreads();
        if (wid == 0) {
            f32x4 a2[2][3];
            #pragma unroll
            for (int m = 0; m < 2; m++)
                #pragma unroll
                for (int g = 0; g < 3; g++)
                    a2[m][g] = red[0][m * 3 + g][lane] + red[1][m * 3 + g][lane]
                             + red[2][m * 3 + g][lane] + red[3][m * 3 + g][lane];
            const float* gid = gi + ((int64_t)d * LI * NB + (int64_t)t * NB) * (3 * HHD);
            #pragma unroll
            for (int mt = 0; mt < 2; mt++)
                #pragma unroll
                for (int r = 0; r < 4; r++) {
                    const int b = mt * 16 + (lane >> 4) * 4 + r;
                    const float ir  = gid[b * 3 * HHD + j];
                    const float iz  = gid[b * 3 * HHD + HHD + j];
                    const float inn = gid[b * 3 * HHD + 2 * HHD + j];
                    const float rg = sigm(ir + a2[mt][0][r] + br);
                    const float zg = sigm(iz + a2[mt][1][r] + bz);
                    const float ng = tanhf(inn + rg * (a2[mt][2][r] + bn));
                    const float hold = h32[hbase + (int64_t)b * HHD + j];
                    const float hnew = (1.f - zg) * ng + zg * hold;
                    const int64_t no = (int64_t)(npar * 2 + d) * NB * HHD + (int64_t)b * HHD + j;
                    bf16 hh = f2b(hnew);
                    bf16 hl = f2b(hnew - b2f(hh));
                    h32[no] = hnew;
                    const float hn2 = __shfl_xor(hnew, 1);
                    if (!(lane & 1)) {
                        bf16 hh2 = f2b(hn2);
                        bf16 hl2 = f2b(hn2 - b2f(hh2));
                        stc2(hHi + no, hh, hh2);
                        stc2(hLo + no, hl, hl2);
                    }
                    Y[((int64_t)t * NB + b) * HD + d * HHD + j] = hnew;
                    if (s == LI - 1) {
                        const int64_t dof = (int64_t)b * HD + d * HHD + j;
                        dh32[dof] = hnew;
                        dhHi[dof] = hh;
                        dhLo[dof] = hl;
                    }
                }
        }
        if (s < LI - 1) gbar(&bar[s], 64);
    }
}

// =====================================================================
// Persistent decoder, W in registers, coherent exchange, ONE global
// barrier/iter; kh0<->kh1 PART hand-off via per-pair flag.
// Grid (HD/16=64, 3) x 512 thr.
// =====================================================================
__global__ __launch_bounds__(512, 1) void dec_persist_k(
    const float* __restrict__ gi0,
    const bf16* __restrict__ wih1Hi, const bf16* __restrict__ wih1Lo,
    const bf16* __restrict__ whh0Hi, const bf16* __restrict__ whh0Lo,
    const bf16* __restrict__ whh1Hi, const bf16* __restrict__ whh1Lo,
    const float* __restrict__ bih1,
    const float* __restrict__ bhh0,
    const float* __restrict__ bhh1,
    float* __restrict__ h32,
    bf16* __restrict__ hHi, bf16* __restrict__ hLo,
    float* __restrict__ rnn,
    f32x4* __restrict__ part,         // [64 j][8 grp][64 lane]
    int* __restrict__ bar,            // [LO] global-step counters
    int* __restrict__ flagd)          // [64] kh1->kh0 per-pair flags
{
    __shared__ f32x4 red[8][8][64];   // 64 KiB
    const int tid = threadIdx.x;
    const int lane = tid & 63, wid = tid >> 6;
    const int r16 = lane & 15, k8 = (lane >> 4) * 8;
    const int j0 = blockIdx.x * 16;
    const int j = j0 + r16;
    const int NBLK = 64 * 3;

    if (blockIdx.y == 0) {
        const int kq = wid * 128;
        bf16x8 wh[3][4], wl[3][4];
        #pragma unroll
        for (int g = 0; g < 3; g++)
            #pragma unroll
            for (int kk = 0; kk < 4; kk++) {
                const int64_t wo = (int64_t)(g * HD + j0 + r16) * HD + kq + kk * 32 + k8;
                wh[g][kk] = ld8(whh0Hi + wo);
                wl[g][kk] = ld8(whh0Lo + wo);
            }
        const float b0r = bhh0[j], b0z = bhh0[HD + j], b0n = bhh0[2 * HD + j];

        for (int s = 0; s <= LO; s++) {
            if (s < LO) {
                const int t = s, par = t & 1, npar = par ^ 1;
                const int64_t hb = (int64_t)(par * NLAY + 0) * NB * HD;
                f32x4 acc[2][3];
                #pragma unroll
                for (int m = 0; m < 2; m++)
                    #pragma unroll
                    for (int g = 0; g < 3; g++) acc[m][g] = f32x4{0.f, 0.f, 0.f, 0.f};
                #pragma unroll
                for (int kk = 0; kk < 4; kk++) {
                    const int64_t o0 = hb + (int64_t)r16 * HD + kq + kk * 32 + k8;
                    const int64_t o1 = hb + (int64_t)(16 + r16) * HD + kq + kk * 32 + k8;
                    bf16x8 a0h = ldc(hHi + o0), a0l = ldc(hLo + o0);
                    bf16x8 a1h = ldc(hHi + o1), a1l = ldc(hLo + o1);
                    #pragma unroll
                    for (int g = 0; g < 3; g++) {
                        acc[0][g] = mfma3(a0h, a0l, wh[g][kk], wl[g][kk], acc[0][g]);
                        acc[1][g] = mfma3(a1h, a1l, wh[g][kk], wl[g][kk], acc[1][g]);
                    }
                }
                #pragma unroll
                for (int m = 0; m < 2; m++)
                    #pragma unroll
                    for (int g = 0; g < 3; g++)
                        red[wid][m * 3 + g][lane] = acc[m][g];
                __syncthreads();
                if (wid == 0) {
                    f32x4 a2[2][3];
                    #pragma unroll
                    for (int m = 0; m < 2; m++)
                        #pragma unroll
                        for (int g = 0; g < 3; g++) {
                            f32x4 v = red[0][m * 3 + g][lane];
                            #pragma unroll
                            for (int w2 = 1; w2 < 8; w2++) v += red[w2][m * 3 + g][lane];
                            a2[m][g] = v;
                        }
                    const float* gid = gi0 + (int64_t)t * NB * 3 * HD;
                    #pragma unroll
                    for (int mt = 0; mt < 2; mt++)
                        #pragma unroll
                        for (int r = 0; r < 4; r++) {
                            const int b = mt * 16 + (lane >> 4) * 4 + r;
                            const float ir  = gid[b * 3 * HD + j];
                            const float iz  = gid[b * 3 * HD + HD + j];
                            const float inn = gid[b * 3 * HD + 2 * HD + j];
                            const float rg = sigm(ir + a2[mt][0][r] + b0r);
                            const float zg = sigm(iz + a2[mt][1][r] + b0z);
                            const float ng = tanhf(inn + rg * (a2[mt][2][r] + b0n));
                            const float hold = h32[hb + (int64_t)b * HD + j];
                            const float hnew = (1.f - zg) * ng + zg * hold;
                            const int64_t no = (int64_t)(npar * NLAY + 0) * NB * HD + (int64_t)b * HD + j;
                            bf16 hh = f2b(hnew);
                            bf16 hl = f2b(hnew - b2f(hh));
                            h32[no] = hnew;
                            const float hn2 = __shfl_xor(hnew, 1);
                            if (!(lane & 1)) {
                                bf16 hh2 = f2b(hn2);
                                bf16 hl2 = f2b(hn2 - b2f(hh2));
                                stc2(hHi + no, hh, hh2);
                                stc2(hLo + no, hl, hl2);
                            }
                        }
                }
            }
            if (s < LO) gbar(&bar[s], NBLK);
        }
    } else {
        const int kh = blockIdx.y - 1;
        const int kb = kh * 512 + wid * 64;
        bf16x8 wIh[3][2], wIl[3][2], wHh[3][2], wHl[3][2];
        #pragma unroll
        for (int g = 0; g < 3; g++)
            #pragma unroll
            for (int kk = 0; kk < 2; kk++) {
                const int64_t wo = (int64_t)(g * HD + j0 + r16) * HD + kb + kk * 32 + k8;
                wIh[g][kk] = ld8(wih1Hi + wo);
                wIl[g][kk] = ld8(wih1Lo + wo);
                wHh[g][kk] = ld8(whh1Hi + wo);
                wHl[g][kk] = ld8(whh1Lo + wo);
            }
        const float brr = bih1[j] + bhh1[j];
        const float bzz = bih1[HD + j] + bhh1[HD + j];
        const float bin = bih1[2 * HD + j];
        const float bhn = bhh1[2 * HD + j];

        for (int s = 0; s <= LO; s++) {
            if (s >= 1) {
                const int t = s - 1;
                const int p0 = (t + 1) & 1;
                const int p1 = t & 1, np1 = p1 ^ 1;
                const int64_t h0b = (int64_t)(p0 * NLAY + 0) * NB * HD;
                const int64_t h1b = (int64_t)(p1 * NLAY + 1) * NB * HD;
                f32x4 arz[2][2], ain[2], ahn[2];
                #pragma unroll
                for (int i = 0; i < 2; i++) {
                    arz[i][0] = f32x4{0.f, 0.f, 0.f, 0.f};
                    arz[i][1] = f32x4{0.f, 0.f, 0.f, 0.f};
                    ain[i] = f32x4{0.f, 0.f, 0.f, 0.f};
                    ahn[i] = f32x4{0.f, 0.f, 0.f, 0.f};
                }
                #pragma unroll
                for (int kk = 0; kk < 2; kk++) {
                    const int64_t xo0 = h0b + (int64_t)r16 * HD + kb + kk * 32 + k8;
                    const int64_t xo1 = h0b + (int64_t)(16 + r16) * HD + kb + kk * 32 + k8;
                    const int64_t yo0 = h1b + (int64_t)r16 * HD + kb + kk * 32 + k8;
                    const int64_t yo1 = h1b + (int64_t)(16 + r16) * HD + kb + kk * 32 + k8;
                    bf16x8 x0h = ldc(hHi + xo0), x0l = ldc(hLo + xo0);
                    bf16x8 x1h = ldc(hHi + xo1), x1l = ldc(hLo + xo1);
                    bf16x8 y0h = ldc(hHi + yo0), y0l = ldc(hLo + yo0);
                    bf16x8 y1h = ldc(hHi + yo1), y1l = ldc(hLo + yo1);
                    arz[0][0] = mfma3(x0h, x0l, wIh[0][kk], wIl[0][kk], arz[0][0]);
                    arz[0][0] = mfma3(y0h, y0l, wHh[0][kk], wHl[0][kk], arz[0][0]);
                    arz[1][0] = mfma3(x1h, x1l, wIh[0][kk], wIl[0][kk], arz[1][0]);
                    arz[1][0] = mfma3(y1h, y1l, wHh[0][kk], wHl[0][kk], arz[1][0]);
                    arz[0][1] = mfma3(x0h, x0l, wIh[1][kk], wIl[1][kk], arz[0][1]);
                    arz[0][1] = mfma3(y0h, y0l, wHh[1][kk], wHl[1][kk], arz[0][1]);
                    arz[1][1] = mfma3(x1h, x1l, wIh[1][kk], wIl[1][kk], arz[1][1]);
                    arz[1][1] = mfma3(y1h, y1l, wHh[1][kk], wHl[1][kk], arz[1][1]);
                    ain[0] = mfma3(x0h, x0l, wIh[2][kk], wIl[2][kk], ain[0]);
                    ain[1] = mfma3(x1h, x1l, wIh[2][kk], wIl[2][kk], ain[1]);
                    ahn[0] = mfma3(y0h, y0l, wHh[2][kk], wHl[2][kk], ahn[0]);
                    ahn[1] = mfma3(y1h, y1l, wHh[2][kk], wHl[2][kk], ahn[1]);
                }
                red[wid][0][lane] = arz[0][0];
                red[wid][1][lane] = arz[1][0];
                red[wid][2][lane] = arz[0][1];
                red[wid][3][lane] = arz[1][1];
                red[wid][4][lane] = ain[0];
                red[wid][5][lane] = ain[1];
                red[wid][6][lane] = ahn[0];
                red[wid][7][lane] = ahn[1];
                __syncthreads();
                if (wid == 0) {
                    f32x4 p[8];
                    #pragma unroll
                    for (int grp = 0; grp < 8; grp++) {
                        f32x4 v = red[0][grp][lane];
                        #pragma unroll
                        for (int w2 = 1; w2 < 8; w2++) v += red[w2][grp][lane];
                        p[grp] = v;
                    }
                    if (kh == 1) {
                        #pragma unroll
                        for (int grp = 0; grp < 8; grp++)
                            stc4f((float*)&part[((size_t)blockIdx.x * 8 + grp) * 64 + lane], p[grp]);
                        asm volatile("s_waitcnt vmcnt(0)" ::: "memory");
                        if (lane == 0)
                            __hip_atomic_store(&flagd[blockIdx.x], s, __ATOMIC_RELAXED, __HIP_MEMORY_SCOPE_AGENT);
                    } else {
                        while (__hip_atomic_load(&flagd[blockIdx.x], __ATOMIC_RELAXED, __HIP_MEMORY_SCOPE_AGENT) < s)
                            __builtin_amdgcn_s_sleep(1);
                        asm volatile("" ::: "memory");
                        #pragma unroll
                        for (int grp = 0; grp < 8; grp++)
                            p[grp] += ldc4f((const float*)&part[((size_t)blockIdx.x * 8 + grp) * 64 + lane]);
                        #pragma unroll
                        for (int mt = 0; mt < 2; mt++)
                            #pragma unroll
                            for (int r = 0; r < 4; r++) {
                                const int b = mt * 16 + (lane >> 4) * 4 + r;
                                const float rg = sigm(p[0 + mt][r] + brr);
                                const float zg = sigm(p[2 + mt][r] + bzz);
                                const float ng = tanhf(p[4 + mt][r] + bin + rg * (p[6 + mt][r] + bhn));
                                const float hold = h32[h1b + (int64_t)b * HD + j];
                                const float hnew = (1.f - zg) * ng + zg * hold;
                                const int64_t no = (int64_t)(np1 * NLAY + 1) * NB * HD + (int64_t)b * HD + j;
                                bf16 hh = f2b(hnew);
                                bf16 hl = f2b(hnew - b2f(hh));
                                h32[no] = hnew;
                                const float hn2 = __shfl_xor(hnew, 1);
                                if (!(lane & 1)) {
                                    bf16 hh2 = f2b(hn2);
                                    bf16 hl2 = f2b(hn2 - b2f(hh2));
                                    stc2(hHi + no, hh, hh2);
                                    stc2(hLo + no, hl, hl2);
                                }
                                rnn[((int64_t)t * NB + b) * HD + j] = hnew;
                            }
                    }
                }
            }
            if (s < LO) gbar(&bar[s], NBLK);
        }
    }
}

// =====================================================================
__global__ __launch_bounds__(64) void softmax_k(const float* __restrict__ sc,
                                                float* __restrict__ aout)
{
    const int row = blockIdx.x, l = threadIdx.x;
    float v0 = sc[row * LI + l], v1 = sc[row * LI + 64 + l];
    float m = fmaxf(v0, v1);
    #pragma unroll
    for (int o = 32; o > 0; o >>= 1) m = fmaxf(m, __shfl_xor(m, o));
    float e0 = expf(v0 - m), e1 = expf(v1 - m);
    float s = e0 + e1;
    #pragma unroll
    for (int o = 32; o > 0; o >>= 1) s += __shfl_xor(s, o);
    const float inv = 1.f / s;
    aout[row * LI + l] = e0 * inv;
    aout[row * LI + 64 + l] = e1 * inv;
}

__global__ __launch_bounds__(256) void ctx_k(const float* __restrict__ at,
                                             const float* __restrict__ enc,
                                             float* __restrict__ jin)
{
    const int b = blockIdx.y, h0 = blockIdx.x * 128;
    __shared__ __align__(16) float al[LO][LI];
    for (int i = threadIdx.x; i < LO * LI; i += 256) {
        const int to = i >> 7, ti = i & 127;
        al[to][ti] = at[(to * NB + b) * LI + ti];
    }
    __syncthreads();
    const int hc = h0 + (threadIdx.x & 127);
    const int rh = threadIdx.x >> 7;
    float acc[32];
    #pragma unroll
    for (int i = 0; i < 32; i++) acc[i] = 0.f;
    for (int t = 0; t < LI; t++) {
        const float ev = enc[((int64_t)t * NB + b) * HD + hc];
        #pragma unroll
        for (int i = 0; i < 32; i++) acc[i] += ev * al[rh * 32 + i][t];
    }
    #pragma unroll
    for (int i = 0; i < 32; i++)
        jin[((int64_t)(rh * 32 + i) * NB + b) * (2 * HD) + hc] = acc[i];
}

__global__ void rnncopy_k(const float* __restrict__ rnn, float* __restrict__ jin)
{
    const int idx = blockIdx.x * 256 + threadIdx.x;
    const int row = idx >> 8;
    const int c = idx & 255;
    ((uint4*)jin)[(int64_t)row * 512 + 256 + c] = ((const uint4*)rnn)[idx];
}

// =====================================================================
extern "C" void kernel_launch(void* const* d_in, const int* in_sizes, int n_in,
                              void* d_out, int out_size, void* d_ws, size_t ws_size,
                              hipStream_t stream)
{
    (void)in_sizes; (void)n_in; (void)out_size; (void)ws_size;
    const int*   in_tok   = (const int*)d_in[0];
    const int*   out_tok  = (const int*)d_in[2];
    const float* enc_emb  = (const float*)d_in[4];
    const float* enc_wih  = (const float*)d_in[5];
    const float* enc_whh  = (const float*)d_in[6];
    const float* enc_bih  = (const float*)d_in[7];
    const float* enc_bhh  = (const float*)d_in[8];
    const float* dec_emb  = (const float*)d_in[9];
    const float* dec_wih  = (const float*)d_in[10];
    const float* dec_whh  = (const float*)d_in[11];
    const float* dec_bih  = (const float*)d_in[12];
    const float* dec_bhh  = (const float*)d_in[13];
    const float* attn_W   = (const float*)d_in[14];
    const float* joiner_W = (const float*)d_in[15];
    const float* joiner_b = (const float*)d_in[16];
    const float* proj_W   = (const float*)d_in[17];
    const float* proj_b   = (const float*)d_in[18];
    float* logits   = (float*)d_out;
    float* attn_out = logits + (size_t)LO * NB * NV;

    const size_t MB = 1ull << 20;
    char* o = (char*)d_out;
    float* XB0   = (float*)(o);              // 16 MiB enc embedded input
    float* XB1   = (float*)(o + 16 * MB);    // 16 MiB enc layer0 output
    float* EOUT  = (float*)(o + 32 * MB);    // 16 MiB enc_outputs
    float* PENC  = (float*)(o + 48 * MB);    // 16 MiB proj_enc
    float* GI    = (float*)(o + 64 * MB);    // 48 MiB enc gi (both dirs)
    float* DEMB  = (float*)(o + 112 * MB);   //  8 MiB dec embedded
    float* DGI0  = (float*)(o + 120 * MB);   // 24 MiB dec layer0 gi
    float* RNN   = (float*)(o + 144 * MB);   //  8 MiB rnn_out
    float* SC    = (float*)(o + 152 * MB);   //  1 MiB scores
    float* JIN   = (float*)(o + 153 * MB);   // 16 MiB cat(ctx, rnn)
    bf16* WencHi = (bf16*)(o + 169 * MB);    //  6 MiB enc_whh hi
    bf16* WencLo = (bf16*)(o + 175 * MB);    //  6 MiB enc_whh lo
    bf16* WdhHi  = (bf16*)(o + 181 * MB);    // 12 MiB dec_whh hi
    bf16* WdhLo  = (bf16*)(o + 193 * MB);    // 12 MiB dec_whh lo
    bf16* Wih1Hi = (bf16*)(o + 205 * MB);    //  6 MiB dec_wih[1] hi
    bf16* Wih1Lo = (bf16*)(o + 211 * MB);    //  6 MiB dec_wih[1] lo
    int*  BAR_E0 = (int*)(o + 218 * MB);     // 128
    int*  BAR_E1 = BAR_E0 + 128;             // 128
    int*  BAR_D  = BAR_E0 + 256;             // 64
    int*  FLAGD  = BAR_E0 + 320;             // 64
    f32x4* PART  = (f32x4*)(o + 219 * MB);   // 512 KiB layer1 partials

    char* w = (char*)d_ws;                   // 10 MiB total
    float* VECS = (float*)(w);                       // 8 MiB tanh(joiner)
    float* EH32 = (float*)(w + 8 * MB);              // 512 KiB
    bf16*  EHhi = (bf16*) (w + 8 * MB + 524288);     // 256 KiB
    bf16*  EHlo = (bf16*) (w + 8 * MB + 786432);     // 256 KiB
    float* DH32 = (float*)(w + 9 * MB);              // 512 KiB
    bf16*  DHhi = (bf16*) (w + 9 * MB + 524288);     // 256 KiB
    bf16*  DHlo = (bf16*) (w + 9 * MB + 786432);     // 256 KiB

    hipMemsetAsync(BAR_E0, 0, 384 * sizeof(int), stream);

    // ---- pre-split recurrent weights ----
    const int nEnc = NLAY * 2 * 3 * HHD * HHD;
    const int nDhh = NLAY * 3 * HD * HD;
    const int nIh1 = 3 * HD * HD;
    presplit_k<<<dim3((nEnc + 255) / 256), dim3(256), 0, stream>>>(enc_whh, WencHi, WencLo, nEnc);
    presplit_k<<<dim3((nDhh + 255) / 256), dim3(256), 0, stream>>>(dec_whh, WdhHi, WdhLo, nDhh);
    presplit_k<<<dim3((nIh1 + 255) / 256), dim3(256), 0, stream>>>(dec_wih + (size_t)3 * HD * HD, Wih1Hi, Wih1Lo, nIh1);

    // ---- decoder prep ----
    embed_k<<<dim3(LO * NB), dim3(256), 0, stream>>>(out_tok, dec_emb, DEMB, 1);
    gemm_k<128, true, false><<<dim3(3 * HD / 128, LO * NB / 128, 1), 256, 0, stream>>>(
        DEMB, HD, 0, dec_wih, HD, 0, DGI0, 3 * HD, 0, dec_bih, 0, HD);

    // ---- encoder ----
    embed_k<<<dim3(LI * NB), dim3(256), 0, stream>>>(in_tok, enc_emb, XB0, 0);
    for (int l = 0; l < NLAY; l++) {
        const float* Xin = l ? XB1 : XB0;
        float* Yout = l ? EOUT : XB1;
        hipMemsetAsync(EH32, 0, (size_t)2 * 2 * NB * HHD * 4, stream);
        hipMemsetAsync(EHhi, 0, (size_t)2 * 2 * NB * HHD * 2, stream);
        hipMemsetAsync(EHlo, 0, (size_t)2 * 2 * NB * HHD * 2, stream);
        gemm_k<128, true, false><<<dim3(3 * HHD / 128, LI * NB / 128, 2), 256, 0, stream>>>(
            Xin, HD, 0,
            enc_wih + (size_t)l * 2 * 3 * HHD * HD, HD, (int64_t)3 * HHD * HD,
            GI, 3 * HHD, (int64_t)LI * NB * 3 * HHD,
            enc_bih + l * 2 * 3 * HHD, 3 * HHD, HD);
        enc_persist_k<<<dim3(HHD / 16, 2), dim3(256), 0, stream>>>(
            GI,
            WencHi + (size_t)l * 2 * 3 * HHD * HHD,
            WencLo + (size_t)l * 2 * 3 * HHD * HHD,
            enc_bhh + l * 2 * 3 * HHD,
            EH32, EHhi, EHlo, Yout,
            DH32 + (size_t)l * NB * HD, DHhi + (size_t)l * NB * HD,
            DHlo + (size_t)l * NB * HD,
            l ? BAR_E1 : BAR_E0);
    }

    // proj_enc = enc_outputs @ attn_W^T
    gemm_k<128, false, false><<<dim3(HD / 128, LI * NB / 128, 1), 256, 0, stream>>>(
        EOUT, HD, 0, attn_W, HD, 0, PENC, HD, 0, nullptr, 0, HD);

    // ---- decoder recurrence (persistent, W-in-regs, coherent exchange) ----
    dec_persist_k<<<dim3(HD / 16, 3), dim3(512), 0, stream>>>(
        DGI0,
        Wih1Hi, Wih1Lo,
        WdhHi, WdhLo,
        WdhHi + (size_t)3 * HD * HD, WdhLo + (size_t)3 * HD * HD,
        dec_bih + 3 * HD, dec_bhh, dec_bhh + 3 * HD,
        DH32, DHhi, DHlo, RNN, PART, BAR_D, FLAGD);

    // ---- batched epilogue ----
    gemm_k<64, false, false><<<dim3(1, 1, NB), 256, 0, stream>>>(
        RNN, (int64_t)NB * HD, HD, PENC, (int64_t)NB * HD, HD,
        SC, (int64_t)NB * LI, LI, nullptr, 0, HD);
    softmax_k<<<dim3(LO * NB), dim3(64), 0, stream>>>(SC, attn_out);
    ctx_k<<<dim3(HD / 128, NB), dim3(256), 0, stream>>>(attn_out, EOUT, JIN);
    rnncopy_k<<<dim3(LO * NB * HD / 4 / 256), dim3(256), 0, stream>>>(RNN, JIN);
    gemm_k<128, true, true><<<dim3(HD / 128, LO * NB / 128, 1), 256, 0, stream>>>(
        JIN, 2 * HD, 0, joiner_W, 2 * HD, 0, VECS, HD, 0, joiner_b, 0, 2 * HD);
    gemm_k<128, true, false><<<dim3(NV / 128, LO * NB / 128, 1), 256, 0, stream>>>(
        VECS, HD, 0, proj_W, HD, 0, logits, NV, 0, proj_b, 0, HD);
}

// Round 8
// 5921.096 us; speedup vs baseline: 1.7861x; 1.0307x over previous
//
#include <hip/hip_runtime.h>
#include <hip/hip_bf16.h>
#include <stdint.h>

// ---- problem constants ----
constexpr int LI   = 128;    // L_IN
constexpr int LO   = 64;     // L_OUT
constexpr int NB   = 32;     // batch
constexpr int HD   = 1024;   // H
constexpr int HHD  = 512;    // HH
constexpr int NLAY = 2;
constexpr int NV   = 32000;  // V_OUT
constexpr int SOST = 1;

// FP32 tensors; bf16x3 split MFMA. Persistent recurrence: W in registers,
// h exchanged via agent-scope (L3) atomics. Round-8: flag/epoch barrier
// (round-7 counters showed the single atomic counter serialized 192 RMWs
// ~30us/iter; per-block flags + master-released epoch are contention-free).

typedef __hip_bfloat16 bf16;
typedef __attribute__((ext_vector_type(8))) short bf16x8;
typedef __attribute__((ext_vector_type(4))) float f32x4;
typedef unsigned long long u64;

__device__ __forceinline__ float b2f(bf16 x) { return __bfloat162float(x); }
__device__ __forceinline__ bf16  f2b(float x) { return __float2bfloat16(x); }
__device__ __forceinline__ float sigm(float x) { return 1.0f / (1.0f + expf(-x)); }

__device__ __forceinline__ f32x4 mfma(bf16x8 a, bf16x8 b, f32x4 c) {
    return __builtin_amdgcn_mfma_f32_16x16x32_bf16(a, b, c, 0, 0, 0);
}
__device__ __forceinline__ f32x4 mfma3(bf16x8 ah, bf16x8 al, bf16x8 bh, bf16x8 bl, f32x4 c) {
    c = mfma(ah, bh, c);
    c = mfma(ah, bl, c);
    c = mfma(al, bh, c);
    return c;
}
__device__ __forceinline__ bf16x8 ld8(const bf16* p) { return *(const bf16x8*)p; }

// ---- coherent (agent/L3) exchange helpers ----
__device__ __forceinline__ bf16x8 ldc(const bf16* p) {
    union { bf16x8 v; u64 q[2]; } u;
    u.q[0] = __hip_atomic_load((const u64*)p,     __ATOMIC_RELAXED, __HIP_MEMORY_SCOPE_AGENT);
    u.q[1] = __hip_atomic_load((const u64*)p + 1, __ATOMIC_RELAXED, __HIP_MEMORY_SCOPE_AGENT);
    return u.v;
}
__device__ __forceinline__ void stc2(bf16* p, bf16 a, bf16 b) {
    unsigned v = (unsigned)*(const unsigned short*)&a |
                 ((unsigned)*(const unsigned short*)&b << 16);
    __hip_atomic_store((unsigned*)p, v, __ATOMIC_RELAXED, __HIP_MEMORY_SCOPE_AGENT);
}
__device__ __forceinline__ f32x4 ldc4f(const float* p) {
    union { f32x4 v; u64 q[2]; } u;
    u.q[0] = __hip_atomic_load((const u64*)p,     __ATOMIC_RELAXED, __HIP_MEMORY_SCOPE_AGENT);
    u.q[1] = __hip_atomic_load((const u64*)p + 1, __ATOMIC_RELAXED, __HIP_MEMORY_SCOPE_AGENT);
    return u.v;
}
__device__ __forceinline__ void stc4f(float* p, f32x4 v) {
    union { f32x4 v; u64 q[2]; } u;
    u.v = v;
    __hip_atomic_store((u64*)p,     u.q[0], __ATOMIC_RELAXED, __HIP_MEMORY_SCOPE_AGENT);
    __hip_atomic_store((u64*)p + 1, u.q[1], __ATOMIC_RELAXED, __HIP_MEMORY_SCOPE_AGENT);
}

__device__ __forceinline__ void split8(const float* p, bf16x8& h8, bf16x8& l8) {
    #pragma unroll
    for (int j = 0; j < 8; j++) {
        float v = p[j];
        bf16 h = f2b(v);
        bf16 l = f2b(v - b2f(h));
        ((bf16*)&h8)[j] = h;
        ((bf16*)&l8)[j] = l;
    }
}

// ---- contention-free grid barrier: per-block flag arrival (parallel
// stores), master wave polls all flags, releases monotonic epoch;
// consumers poll epoch (read-only). No RMW on a shared line.
__device__ __forceinline__ void gbar2(int* __restrict__ flags, int* __restrict__ epoch,
                                      int nblk, int myid, int val, bool master) {
    __syncthreads();
    const int tid = threadIdx.x;
    if (tid < 64) {   // wave 0
        if (tid == 0) {
            asm volatile("s_waitcnt vmcnt(0)" ::: "memory");
            __hip_atomic_store(&flags[myid], val, __ATOMIC_RELAXED, __HIP_MEMORY_SCOPE_AGENT);
        }
        if (master) {
            bool done = false;
            while (!done) {
                bool ok = true;
                for (int i = tid; i < nblk; i += 64)
                    ok &= (__hip_atomic_load(&flags[i], __ATOMIC_RELAXED, __HIP_MEMORY_SCOPE_AGENT) >= val);
                done = __all(ok);
                if (!done) __builtin_amdgcn_s_sleep(1);
            }
            if (tid == 0)
                __hip_atomic_store(epoch, val, __ATOMIC_RELAXED, __HIP_MEMORY_SCOPE_AGENT);
        } else if (tid == 0) {
            while (__hip_atomic_load(epoch, __ATOMIC_RELAXED, __HIP_MEMORY_SCOPE_AGENT) < val)
                __builtin_amdgcn_s_sleep(1);
        }
        asm volatile("" ::: "memory");
    }
    __syncthreads();
}

// =====================================================================
// Split-precision MFMA GEMM (unchanged).
// =====================================================================
template<int BM, bool BIAS, bool TANH>
__global__ __launch_bounds__(256) void gemm_k(
    const float* __restrict__ A, int64_t lda, int64_t sA,
    const float* __restrict__ W, int64_t ldw, int64_t sW,
    float* __restrict__ C, int64_t ldc, int64_t sC,
    const float* __restrict__ bias, int64_t sBias,
    int K)
{
    constexpr int FM = BM / 32;
    __shared__ __align__(16) bf16 Ahi[BM * 32], Alo[BM * 32];
    __shared__ __align__(16) bf16 Whi[128 * 32], Wlo[128 * 32];
    const int z    = blockIdx.z;
    const float* Ab = A + (int64_t)z * sA;
    const float* Wb = W + (int64_t)z * sW;
    const int n0   = blockIdx.x * 128;
    const int m0   = blockIdx.y * BM;
    const int tid  = threadIdx.x;
    const int lane = tid & 63, wid = tid >> 6;
    const int wm   = wid >> 1, wn = wid & 1;
    const int srow = lane >> 2;
    const int skb  = (lane & 3) * 8;
    const int r16  = lane & 15;
    const int k8   = (lane >> 4) * 8;

    f32x4 acc[FM][4];
    #pragma unroll
    for (int i = 0; i < FM; i++)
        #pragma unroll
        for (int j = 0; j < 4; j++)
            acc[i][j] = f32x4{0.f, 0.f, 0.f, 0.f};

    for (int k0 = 0; k0 < K; k0 += 32) {
        for (int c = wid; c < BM / 16; c += 4) {
            bf16x8 h8, l8;
            split8(Ab + (int64_t)(m0 + c * 16 + srow) * lda + k0 + skb, h8, l8);
            *(bf16x8*)(Ahi + c * 512 + lane * 8) = h8;
            *(bf16x8*)(Alo + c * 512 + lane * 8) = l8;
        }
        for (int c = wid; c < 8; c += 4) {
            bf16x8 h8, l8;
            split8(Wb + (int64_t)(n0 + c * 16 + srow) * ldw + k0 + skb, h8, l8);
            *(bf16x8*)(Whi + c * 512 + lane * 8) = h8;
            *(bf16x8*)(Wlo + c * 512 + lane * 8) = l8;
        }
        __syncthreads();
        bf16x8 afh[FM], afl[FM], wfh[4], wfl[4];
        #pragma unroll
        for (int mt = 0; mt < FM; mt++) {
            const int off = (wm * (BM / 2) + mt * 16 + r16) * 32 + k8;
            afh[mt] = ld8(Ahi + off);
            afl[mt] = ld8(Alo + off);
        }
        #pragma unroll
        for (int nt = 0; nt < 4; nt++) {
            const int off = (wn * 64 + nt * 16 + r16) * 32 + k8;
            wfh[nt] = ld8(Whi + off);
            wfl[nt] = ld8(Wlo + off);
        }
        #pragma unroll
        for (int mt = 0; mt < FM; mt++)
            #pragma unroll
            for (int nt = 0; nt < 4; nt++)
                acc[mt][nt] = mfma3(afh[mt], afl[mt], wfh[nt], wfl[nt], acc[mt][nt]);
        __syncthreads();
    }
    #pragma unroll
    for (int nt = 0; nt < 4; nt++) {
        const int n = n0 + wn * 64 + nt * 16 + r16;
        float bv = 0.f;
        if constexpr (BIAS) bv = bias[(int64_t)z * sBias + n];
        #pragma unroll
        for (int mt = 0; mt < FM; mt++) {
            const int mb = m0 + wm * (BM / 2) + mt * 16 + (lane >> 4) * 4;
            #pragma unroll
            for (int r = 0; r < 4; r++) {
                float v = acc[mt][nt][r] + bv;
                if constexpr (TANH) v = tanhf(v);
                C[(int64_t)z * sC + (int64_t)(mb + r) * ldc + n] = v;
            }
        }
    }
}

__global__ void presplit_k(const float* __restrict__ x, bf16* __restrict__ hi,
                           bf16* __restrict__ lo, int n)
{
    const int i = blockIdx.x * 256 + threadIdx.x;
    if (i < n) {
        float v = x[i];
        bf16 h = f2b(v);
        hi[i] = h;
        lo[i] = f2b(v - b2f(h));
    }
}

__global__ void embed_k(const int* __restrict__ toks, const float* __restrict__ tab,
                        float* __restrict__ out, int shifted)
{
    const int row = blockIdx.x;
    int tok;
    if (shifted) {
        const int t = row / NB, b = row - t * NB;
        tok = (t == 0) ? SOST : toks[(t - 1) * NB + b];
    } else {
        tok = toks[row];
    }
    const uint4* s = (const uint4*)(tab + (int64_t)tok * HD);
    uint4* d = (uint4*)(out + (int64_t)row * HD);
    d[threadIdx.x] = s[threadIdx.x];
}

// =====================================================================
// Persistent encoder layer, W in registers, coherent h exchange,
// flag/epoch barrier. Grid (HHD/16=32, 2 dirs) x 256 thr.
// =====================================================================
__global__ __launch_bounds__(256, 1) void enc_persist_k(
    const float* __restrict__ gi,
    const bf16* __restrict__ whhHi,
    const bf16* __restrict__ whhLo,
    const float* __restrict__ bhh,
    float* __restrict__ h32,
    bf16* __restrict__ hHi, bf16* __restrict__ hLo,
    float* __restrict__ Y,
    float* __restrict__ dh32, bf16* __restrict__ dhHi, bf16* __restrict__ dhLo,
    int* __restrict__ flags, int* __restrict__ epoch)
{
    __shared__ f32x4 red[4][6][64];
    const int d = blockIdx.y;
    const int j0 = blockIdx.x * 16;
    const int tid = threadIdx.x;
    const int lane = tid & 63, wid = tid >> 6;
    const int r16 = lane & 15, k8 = (lane >> 4) * 8;
    const int kq = wid * 128;
    const bf16* WdH = whhHi + (int64_t)d * 3 * HHD * HHD;
    const bf16* WdL = whhLo + (int64_t)d * 3 * HHD * HHD;
    const int j = j0 + r16;
    const int myid = d * 32 + blockIdx.x;
    const bool master = (myid == 0);

    bf16x8 wh[3][4], wl[3][4];
    #pragma unroll
    for (int g = 0; g < 3; g++)
        #pragma unroll
        for (int kk = 0; kk < 4; kk++) {
            const int64_t wo = (int64_t)(g * HHD + j0 + r16) * HHD + kq + kk * 32 + k8;
            wh[g][kk] = ld8(WdH + wo);
            wl[g][kk] = ld8(WdL + wo);
        }
    const float br = bhh[d * 3 * HHD + j];
    const float bz = bhh[d * 3 * HHD + HHD + j];
    const float bn = bhh[d * 3 * HHD + 2 * HHD + j];

    for (int s = 0; s < LI; s++) {
        const int t = d ? (LI - 1 - s) : s;
        const int par = s & 1, npar = par ^ 1;
        const int64_t hbase = (int64_t)(par * 2 + d) * NB * HHD;

        f32x4 acc[2][3];
        #pragma unroll
        for (int m = 0; m < 2; m++)
            #pragma unroll
            for (int g = 0; g < 3; g++) acc[m][g] = f32x4{0.f, 0.f, 0.f, 0.f};

        #pragma unroll
        for (int kk = 0; kk < 4; kk++) {
            const int64_t o0 = hbase + (int64_t)r16 * HHD + kq + kk * 32 + k8;
            const int64_t o1 = hbase + (int64_t)(16 + r16) * HHD + kq + kk * 32 + k8;
            bf16x8 a0h = ldc(hHi + o0), a0l = ldc(hLo + o0);
            bf16x8 a1h = ldc(hHi + o1), a1l = ldc(hLo + o1);
            #pragma unroll
            for (int g = 0; g < 3; g++) {
                acc[0][g] = mfma3(a0h, a0l, wh[g][kk], wl[g][kk], acc[0][g]);
                acc[1][g] = mfma3(a1h, a1l, wh[g][kk], wl[g][kk], acc[1][g]);
            }
        }
        #pragma unroll
        for (int m = 0; m < 2; m++)
            #pragma unroll
            for (int g = 0; g < 3; g++)
                red[wid][m * 3 + g][lane] = acc[m][g];
        __syncthreads();
        if (wid == 0) {
            f32x4 a2[2][3];
            #pragma unroll
            for (int m = 0; m < 2; m++)
                #pragma unroll
                for (int g = 0; g < 3; g++)
                    a2[m][g] = red[0][m * 3 + g][lane] + red[1][m * 3 + g][lane]
                             + red[2][m * 3 + g][lane] + red[3][m * 3 + g][lane];
            const float* gid = gi + ((int64_t)d * LI * NB + (int64_t)t * NB) * (3 * HHD);
            #pragma unroll
            for (int mt = 0; mt < 2; mt++)
                #pragma unroll
                for (int r = 0; r < 4; r++) {
                    const int b = mt * 16 + (lane >> 4) * 4 + r;
                    const float ir  = gid[b * 3 * HHD + j];
                    const float iz  = gid[b * 3 * HHD + HHD + j];
                    const float inn = gid[b * 3 * HHD + 2 * HHD + j];
                    const float rg = sigm(ir + a2[mt][0][r] + br);
                    const float zg = sigm(iz + a2[mt][1][r] + bz);
                    const float ng = tanhf(inn + rg * (a2[mt][2][r] + bn));
                    const float hold = h32[hbase + (int64_t)b * HHD + j];
                    const float hnew = (1.f - zg) * ng + zg * hold;
                    const int64_t no = (int64_t)(npar * 2 + d) * NB * HHD + (int64_t)b * HHD + j;
                    bf16 hh = f2b(hnew);
                    bf16 hl = f2b(hnew - b2f(hh));
                    h32[no] = hnew;
                    const float hn2 = __shfl_xor(hnew, 1);
                    if (!(lane & 1)) {
                        bf16 hh2 = f2b(hn2);
                        bf16 hl2 = f2b(hn2 - b2f(hh2));
                        stc2(hHi + no, hh, hh2);
                        stc2(hLo + no, hl, hl2);
                    }
                    Y[((int64_t)t * NB + b) * HD + d * HHD + j] = hnew;
                    if (s == LI - 1) {
                        const int64_t dof = (int64_t)b * HD + d * HHD + j;
                        dh32[dof] = hnew;
                        dhHi[dof] = hh;
                        dhLo[dof] = hl;
                    }
                }
        }
        if (s < LI - 1) gbar2(flags, epoch, 64, myid, s + 1, master);
    }
}

// =====================================================================
// Persistent decoder, W in registers, coherent exchange, flag/epoch
// barrier; kh0<->kh1 PART hand-off via per-pair flag.
// Grid (HD/16=64, 3) x 512 thr.
// =====================================================================
__global__ __launch_bounds__(512, 1) void dec_persist_k(
    const float* __restrict__ gi0,
    const bf16* __restrict__ wih1Hi, const bf16* __restrict__ wih1Lo,
    const bf16* __restrict__ whh0Hi, const bf16* __restrict__ whh0Lo,
    const bf16* __restrict__ whh1Hi, const bf16* __restrict__ whh1Lo,
    const float* __restrict__ bih1,
    const float* __restrict__ bhh0,
    const float* __restrict__ bhh1,
    float* __restrict__ h32,
    bf16* __restrict__ hHi, bf16* __restrict__ hLo,
    float* __restrict__ rnn,
    f32x4* __restrict__ part,
    int* __restrict__ flags, int* __restrict__ epoch,
    int* __restrict__ flagd)
{
    __shared__ f32x4 red[8][8][64];
    const int tid = threadIdx.x;
    const int lane = tid & 63, wid = tid >> 6;
    const int r16 = lane & 15, k8 = (lane >> 4) * 8;
    const int j0 = blockIdx.x * 16;
    const int j = j0 + r16;
    const int NBLK = 64 * 3;
    const int myid = blockIdx.y * 64 + blockIdx.x;
    const bool master = (myid == 0);

    if (blockIdx.y == 0) {
        const int kq = wid * 128;
        bf16x8 wh[3][4], wl[3][4];
        #pragma unroll
        for (int g = 0; g < 3; g++)
            #pragma unroll
            for (int kk = 0; kk < 4; kk++) {
                const int64_t wo = (int64_t)(g * HD + j0 + r16) * HD + kq + kk * 32 + k8;
                wh[g][kk] = ld8(whh0Hi + wo);
                wl[g][kk] = ld8(whh0Lo + wo);
            }
        const float b0r = bhh0[j], b0z = bhh0[HD + j], b0n = bhh0[2 * HD + j];

        for (int s = 0; s <= LO; s++) {
            if (s < LO) {
                const int t = s, par = t & 1, npar = par ^ 1;
                const int64_t hb = (int64_t)(par * NLAY + 0) * NB * HD;
                f32x4 acc[2][3];
                #pragma unroll
                for (int m = 0; m < 2; m++)
                    #pragma unroll
                    for (int g = 0; g < 3; g++) acc[m][g] = f32x4{0.f, 0.f, 0.f, 0.f};
                #pragma unroll
                for (int kk = 0; kk < 4; kk++) {
                    const int64_t o0 = hb + (int64_t)r16 * HD + kq + kk * 32 + k8;
                    const int64_t o1 = hb + (int64_t)(16 + r16) * HD + kq + kk * 32 + k8;
                    bf16x8 a0h = ldc(hHi + o0), a0l = ldc(hLo + o0);
                    bf16x8 a1h = ldc(hHi + o1), a1l = ldc(hLo + o1);
                    #pragma unroll
                    for (int g = 0; g < 3; g++) {
                        acc[0][g] = mfma3(a0h, a0l, wh[g][kk], wl[g][kk], acc[0][g]);
                        acc[1][g] = mfma3(a1h, a1l, wh[g][kk], wl[g][kk], acc[1][g]);
                    }
                }
                #pragma unroll
                for (int m = 0; m < 2; m++)
                    #pragma unroll
                    for (int g = 0; g < 3; g++)
                        red[wid][m * 3 + g][lane] = acc[m][g];
                __syncthreads();
                if (wid == 0) {
                    f32x4 a2[2][3];
                    #pragma unroll
                    for (int m = 0; m < 2; m++)
                        #pragma unroll
                        for (int g = 0; g < 3; g++) {
                            f32x4 v = red[0][m * 3 + g][lane];
                            #pragma unroll
                            for (int w2 = 1; w2 < 8; w2++) v += red[w2][m * 3 + g][lane];
                            a2[m][g] = v;
                        }
                    const float* gid = gi0 + (int64_t)t * NB * 3 * HD;
                    #pragma unroll
                    for (int mt = 0; mt < 2; mt++)
                        #pragma unroll
                        for (int r = 0; r < 4; r++) {
                            const int b = mt * 16 + (lane >> 4) * 4 + r;
                            const float ir  = gid[b * 3 * HD + j];
                            const float iz  = gid[b * 3 * HD + HD + j];
                            const float inn = gid[b * 3 * HD + 2 * HD + j];
                            const float rg = sigm(ir + a2[mt][0][r] + b0r);
                            const float zg = sigm(iz + a2[mt][1][r] + b0z);
                            const float ng = tanhf(inn + rg * (a2[mt][2][r] + b0n));
                            const float hold = h32[hb + (int64_t)b * HD + j];
                            const float hnew = (1.f - zg) * ng + zg * hold;
                            const int64_t no = (int64_t)(npar * NLAY + 0) * NB * HD + (int64_t)b * HD + j;
                            bf16 hh = f2b(hnew);
                            bf16 hl = f2b(hnew - b2f(hh));
                            h32[no] = hnew;
                            const float hn2 = __shfl_xor(hnew, 1);
                            if (!(lane & 1)) {
                                bf16 hh2 = f2b(hn2);
                                bf16 hl2 = f2b(hn2 - b2f(hh2));
                                stc2(hHi + no, hh, hh2);
                                stc2(hLo + no, hl, hl2);
                            }
                        }
                }
            }
            if (s < LO) gbar2(flags, epoch, NBLK, myid, s + 1, master);
        }
    } else {
        const int kh = blockIdx.y - 1;
        const int kb = kh * 512 + wid * 64;
        bf16x8 wIh[3][2], wIl[3][2], wHh[3][2], wHl[3][2];
        #pragma unroll
        for (int g = 0; g < 3; g++)
            #pragma unroll
            for (int kk = 0; kk < 2; kk++) {
                const int64_t wo = (int64_t)(g * HD + j0 + r16) * HD + kb + kk * 32 + k8;
                wIh[g][kk] = ld8(wih1Hi + wo);
                wIl[g][kk] = ld8(wih1Lo + wo);
                wHh[g][kk] = ld8(whh1Hi + wo);
                wHl[g][kk] = ld8(whh1Lo + wo);
            }
        const float brr = bih1[j] + bhh1[j];
        const float bzz = bih1[HD + j] + bhh1[HD + j];
        const float bin = bih1[2 * HD + j];
        const float bhn = bhh1[2 * HD + j];

        for (int s = 0; s <= LO; s++) {
            if (s >= 1) {
                const int t = s - 1;
                const int p0 = (t + 1) & 1;
                const int p1 = t & 1, np1 = p1 ^ 1;
                const int64_t h0b = (int64_t)(p0 * NLAY + 0) * NB * HD;
                const int64_t h1b = (int64_t)(p1 * NLAY + 1) * NB * HD;
                f32x4 arz[2][2], ain[2], ahn[2];
                #pragma unroll
                for (int i = 0; i < 2; i++) {
                    arz[i][0] = f32x4{0.f, 0.f, 0.f, 0.f};
                    arz[i][1] = f32x4{0.f, 0.f, 0.f, 0.f};
                    ain[i] = f32x4{0.f, 0.f, 0.f, 0.f};
                    ahn[i] = f32x4{0.f, 0.f, 0.f, 0.f};
                }
                #pragma unroll
                for (int kk = 0; kk < 2; kk++) {
                    const int64_t xo0 = h0b + (int64_t)r16 * HD + kb + kk * 32 + k8;
                    const int64_t xo1 = h0b + (int64_t)(16 + r16) * HD + kb + kk * 32 + k8;
                    const int64_t yo0 = h1b + (int64_t)r16 * HD + kb + kk * 32 + k8;
                    const int64_t yo1 = h1b + (int64_t)(16 + r16) * HD + kb + kk * 32 + k8;
                    bf16x8 x0h = ldc(hHi + xo0), x0l = ldc(hLo + xo0);
                    bf16x8 x1h = ldc(hHi + xo1), x1l = ldc(hLo + xo1);
                    bf16x8 y0h = ldc(hHi + yo0), y0l = ldc(hLo + yo0);
                    bf16x8 y1h = ldc(hHi + yo1), y1l = ldc(hLo + yo1);
                    arz[0][0] = mfma3(x0h, x0l, wIh[0][kk], wIl[0][kk], arz[0][0]);
                    arz[0][0] = mfma3(y0h, y0l, wHh[0][kk], wHl[0][kk], arz[0][0]);
                    arz[1][0] = mfma3(x1h, x1l, wIh[0][kk], wIl[0][kk], arz[1][0]);
                    arz[1][0] = mfma3(y1h, y1l, wHh[0][kk], wHl[0][kk], arz[1][0]);
                    arz[0][1] = mfma3(x0h, x0l, wIh[1][kk], wIl[1][kk], arz[0][1]);
                    arz[0][1] = mfma3(y0h, y0l, wHh[1][kk], wHl[1][kk], arz[0][1]);
                    arz[1][1] = mfma3(x1h, x1l, wIh[1][kk], wIl[1][kk], arz[1][1]);
                    arz[1][1] = mfma3(y1h, y1l, wHh[1][kk], wHl[1][kk], arz[1][1]);
                    ain[0] = mfma3(x0h, x0l, wIh[2][kk], wIl[2][kk], ain[0]);
                    ain[1] = mfma3(x1h, x1l, wIh[2][kk], wIl[2][kk], ain[1]);
                    ahn[0] = mfma3(y0h, y0l, wHh[2][kk], wHl[2][kk], ahn[0]);
                    ahn[1] = mfma3(y1h, y1l, wHh[2][kk], wHl[2][kk], ahn[1]);
                }
                red[wid][0][lane] = arz[0][0];
                red[wid][1][lane] = arz[1][0];
                red[wid][2][lane] = arz[0][1];
                red[wid][3][lane] = arz[1][1];
                red[wid][4][lane] = ain[0];
                red[wid][5][lane] = ain[1];
                red[wid][6][lane] = ahn[0];
                red[wid][7][lane] = ahn[1];
                __syncthreads();
                if (wid == 0) {
                    f32x4 p[8];
                    #pragma unroll
                    for (int grp = 0; grp < 8; grp++) {
                        f32x4 v = red[0][grp][lane];
                        #pragma unroll
                        for (int w2 = 1; w2 < 8; w2++) v += red[w2][grp][lane];
                        p[grp] = v;
                    }
                    if (kh == 1) {
                        #pragma unroll
                        for (int grp = 0; grp < 8; grp++)
                            stc4f((float*)&part[((size_t)blockIdx.x * 8 + grp) * 64 + lane], p[grp]);
                        asm volatile("s_waitcnt vmcnt(0)" ::: "memory");
                        if (lane == 0)
                            __hip_atomic_store(&flagd[blockIdx.x], s, __ATOMIC_RELAXED, __HIP_MEMORY_SCOPE_AGENT);
                    } else {
                        while (__hip_atomic_load(&flagd[blockIdx.x], __ATOMIC_RELAXED, __HIP_MEMORY_SCOPE_AGENT) < s)
                            __builtin_amdgcn_s_sleep(1);
                        asm volatile("" ::: "memory");
                        #pragma unroll
                        for (int grp = 0; grp < 8; grp++)
                            p[grp] += ldc4f((const float*)&part[((size_t)blockIdx.x * 8 + grp) * 64 + lane]);
                        #pragma unroll
                        for (int mt = 0; mt < 2; mt++)
                            #pragma unroll
                            for (int r = 0; r < 4; r++) {
                                const int b = mt * 16 + (lane >> 4) * 4 + r;
                                const float rg = sigm(p[0 + mt][r] + brr);
                                const float zg = sigm(p[2 + mt][r] + bzz);
                                const float ng = tanhf(p[4 + mt][r] + bin + rg * (p[6 + mt][r] + bhn));
                                const float hold = h32[h1b + (int64_t)b * HD + j];
                                const float hnew = (1.f - zg) * ng + zg * hold;
                                const int64_t no = (int64_t)(np1 * NLAY + 1) * NB * HD + (int64_t)b * HD + j;
                                bf16 hh = f2b(hnew);
                                bf16 hl = f2b(hnew - b2f(hh));
                                h32[no] = hnew;
                                const float hn2 = __shfl_xor(hnew, 1);
                                if (!(lane & 1)) {
                                    bf16 hh2 = f2b(hn2);
                                    bf16 hl2 = f2b(hn2 - b2f(hh2));
                                    stc2(hHi + no, hh, hh2);
                                    stc2(hLo + no, hl, hl2);
                                }
                                rnn[((int64_t)t * NB + b) * HD + j] = hnew;
                            }
                    }
                }
            }
            if (s < LO) gbar2(flags, epoch, NBLK, myid, s + 1, master);
        }
    }
}

// =====================================================================
__global__ __launch_bounds__(64) void softmax_k(const float* __restrict__ sc,
                                                float* __restrict__ aout)
{
    const int row = blockIdx.x, l = threadIdx.x;
    float v0 = sc[row * LI + l], v1 = sc[row * LI + 64 + l];
    float m = fmaxf(v0, v1);
    #pragma unroll
    for (int o = 32; o > 0; o >>= 1) m = fmaxf(m, __shfl_xor(m, o));
    float e0 = expf(v0 - m), e1 = expf(v1 - m);
    float s = e0 + e1;
    #pragma unroll
    for (int o = 32; o > 0; o >>= 1) s += __shfl_xor(s, o);
    const float inv = 1.f / s;
    aout[row * LI + l] = e0 * inv;
    aout[row * LI + 64 + l] = e1 * inv;
}

__global__ __launch_bounds__(256) void ctx_k(const float* __restrict__ at,
                                             const float* __restrict__ enc,
                                             float* __restrict__ jin)
{
    const int b = blockIdx.y, h0 = blockIdx.x * 128;
    __shared__ __align__(16) float al[LO][LI];
    for (int i = threadIdx.x; i < LO * LI; i += 256) {
        const int to = i >> 7, ti = i & 127;
        al[to][ti] = at[(to * NB + b) * LI + ti];
    }
    __syncthreads();
    const int hc = h0 + (threadIdx.x & 127);
    const int rh = threadIdx.x >> 7;
    float acc[32];
    #pragma unroll
    for (int i = 0; i < 32; i++) acc[i] = 0.f;
    for (int t = 0; t < LI; t++) {
        const float ev = enc[((int64_t)t * NB + b) * HD + hc];
        #pragma unroll
        for (int i = 0; i < 32; i++) acc[i] += ev * al[rh * 32 + i][t];
    }
    #pragma unroll
    for (int i = 0; i < 32; i++)
        jin[((int64_t)(rh * 32 + i) * NB + b) * (2 * HD) + hc] = acc[i];
}

__global__ void rnncopy_k(const float* __restrict__ rnn, float* __restrict__ jin)
{
    const int idx = blockIdx.x * 256 + threadIdx.x;
    const int row = idx >> 8;
    const int c = idx & 255;
    ((uint4*)jin)[(int64_t)row * 512 + 256 + c] = ((const uint4*)rnn)[idx];
}

// =====================================================================
extern "C" void kernel_launch(void* const* d_in, const int* in_sizes, int n_in,
                              void* d_out, int out_size, void* d_ws, size_t ws_size,
                              hipStream_t stream)
{
    (void)in_sizes; (void)n_in; (void)out_size; (void)ws_size;
    const int*   in_tok   = (const int*)d_in[0];
    const int*   out_tok  = (const int*)d_in[2];
    const float* enc_emb  = (const float*)d_in[4];
    const float* enc_wih  = (const float*)d_in[5];
    const float* enc_whh  = (const float*)d_in[6];
    const float* enc_bih  = (const float*)d_in[7];
    const float* enc_bhh  = (const float*)d_in[8];
    const float* dec_emb  = (const float*)d_in[9];
    const float* dec_wih  = (const float*)d_in[10];
    const float* dec_whh  = (const float*)d_in[11];
    const float* dec_bih  = (const float*)d_in[12];
    const float* dec_bhh  = (const float*)d_in[13];
    const float* attn_W   = (const float*)d_in[14];
    const float* joiner_W = (const float*)d_in[15];
    const float* joiner_b = (const float*)d_in[16];
    const float* proj_W   = (const float*)d_in[17];
    const float* proj_b   = (const float*)d_in[18];
    float* logits   = (float*)d_out;
    float* attn_out = logits + (size_t)LO * NB * NV;

    const size_t MB = 1ull << 20;
    char* o = (char*)d_out;
    float* XB0   = (float*)(o);              // 16 MiB enc embedded input
    float* XB1   = (float*)(o + 16 * MB);    // 16 MiB enc layer0 output
    float* EOUT  = (float*)(o + 32 * MB);    // 16 MiB enc_outputs
    float* PENC  = (float*)(o + 48 * MB);    // 16 MiB proj_enc
    float* GI    = (float*)(o + 64 * MB);    // 48 MiB enc gi (both dirs)
    float* DEMB  = (float*)(o + 112 * MB);   //  8 MiB dec embedded
    float* DGI0  = (float*)(o + 120 * MB);   // 24 MiB dec layer0 gi
    float* RNN   = (float*)(o + 144 * MB);   //  8 MiB rnn_out
    float* SC    = (float*)(o + 152 * MB);   //  1 MiB scores
    float* JIN   = (float*)(o + 153 * MB);   // 16 MiB cat(ctx, rnn)
    bf16* WencHi = (bf16*)(o + 169 * MB);    //  6 MiB enc_whh hi
    bf16* WencLo = (bf16*)(o + 175 * MB);    //  6 MiB enc_whh lo
    bf16* WdhHi  = (bf16*)(o + 181 * MB);    // 12 MiB dec_whh hi
    bf16* WdhLo  = (bf16*)(o + 193 * MB);    // 12 MiB dec_whh lo
    bf16* Wih1Hi = (bf16*)(o + 205 * MB);    //  6 MiB dec_wih[1] hi
    bf16* Wih1Lo = (bf16*)(o + 211 * MB);    //  6 MiB dec_wih[1] lo
    int*  FL_E0  = (int*)(o + 218 * MB);     // [0..63]   enc L0 flags
    int*  EP_E0  = FL_E0 + 64;               // [64]      enc L0 epoch
    int*  FL_E1  = FL_E0 + 128;              // [128..191] enc L1 flags
    int*  EP_E1  = FL_E0 + 192;              // [192]
    int*  FL_D   = FL_E0 + 256;              // [256..447] dec flags
    int*  EP_D   = FL_E0 + 448;              // [448]
    int*  FLAGD  = FL_E0 + 512;              // [512..575] kh1->kh0 flags
    f32x4* PART  = (f32x4*)(o + 219 * MB);   // 512 KiB layer1 partials

    char* w = (char*)d_ws;                   // 10 MiB total
    float* VECS = (float*)(w);                       // 8 MiB tanh(joiner)
    float* EH32 = (float*)(w + 8 * MB);              // 512 KiB
    bf16*  EHhi = (bf16*) (w + 8 * MB + 524288);     // 256 KiB
    bf16*  EHlo = (bf16*) (w + 8 * MB + 786432);     // 256 KiB
    float* DH32 = (float*)(w + 9 * MB);              // 512 KiB
    bf16*  DHhi = (bf16*) (w + 9 * MB + 524288);     // 256 KiB
    bf16*  DHlo = (bf16*) (w + 9 * MB + 786432);     // 256 KiB

    hipMemsetAsync(FL_E0, 0, 576 * sizeof(int), stream);

    // ---- pre-split recurrent weights ----
    const int nEnc = NLAY * 2 * 3 * HHD * HHD;
    const int nDhh = NLAY * 3 * HD * HD;
    const int nIh1 = 3 * HD * HD;
    presplit_k<<<dim3((nEnc + 255) / 256), dim3(256), 0, stream>>>(enc_whh, WencHi, WencLo, nEnc);
    presplit_k<<<dim3((nDhh + 255) / 256), dim3(256), 0, stream>>>(dec_whh, WdhHi, WdhLo, nDhh);
    presplit_k<<<dim3((nIh1 + 255) / 256), dim3(256), 0, stream>>>(dec_wih + (size_t)3 * HD * HD, Wih1Hi, Wih1Lo, nIh1);

    // ---- decoder prep ----
    embed_k<<<dim3(LO * NB), dim3(256), 0, stream>>>(out_tok, dec_emb, DEMB, 1);
    gemm_k<128, true, false><<<dim3(3 * HD / 128, LO * NB / 128, 1), 256, 0, stream>>>(
        DEMB, HD, 0, dec_wih, HD, 0, DGI0, 3 * HD, 0, dec_bih, 0, HD);

    // ---- encoder ----
    embed_k<<<dim3(LI * NB), dim3(256), 0, stream>>>(in_tok, enc_emb, XB0, 0);
    for (int l = 0; l < NLAY; l++) {
        const float* Xin = l ? XB1 : XB0;
        float* Yout = l ? EOUT : XB1;
        hipMemsetAsync(EH32, 0, (size_t)2 * 2 * NB * HHD * 4, stream);
        hipMemsetAsync(EHhi, 0, (size_t)2 * 2 * NB * HHD * 2, stream);
        hipMemsetAsync(EHlo, 0, (size_t)2 * 2 * NB * HHD * 2, stream);
        gemm_k<128, true, false><<<dim3(3 * HHD / 128, LI * NB / 128, 2), 256, 0, stream>>>(
            Xin, HD, 0,
            enc_wih + (size_t)l * 2 * 3 * HHD * HD, HD, (int64_t)3 * HHD * HD,
            GI, 3 * HHD, (int64_t)LI * NB * 3 * HHD,
            enc_bih + l * 2 * 3 * HHD, 3 * HHD, HD);
        enc_persist_k<<<dim3(HHD / 16, 2), dim3(256), 0, stream>>>(
            GI,
            WencHi + (size_t)l * 2 * 3 * HHD * HHD,
            WencLo + (size_t)l * 2 * 3 * HHD * HHD,
            enc_bhh + l * 2 * 3 * HHD,
            EH32, EHhi, EHlo, Yout,
            DH32 + (size_t)l * NB * HD, DHhi + (size_t)l * NB * HD,
            DHlo + (size_t)l * NB * HD,
            l ? FL_E1 : FL_E0, l ? EP_E1 : EP_E0);
    }

    // proj_enc = enc_outputs @ attn_W^T
    gemm_k<128, false, false><<<dim3(HD / 128, LI * NB / 128, 1), 256, 0, stream>>>(
        EOUT, HD, 0, attn_W, HD, 0, PENC, HD, 0, nullptr, 0, HD);

    // ---- decoder recurrence (persistent) ----
    dec_persist_k<<<dim3(HD / 16, 3), dim3(512), 0, stream>>>(
        DGI0,
        Wih1Hi, Wih1Lo,
        WdhHi, WdhLo,
        WdhHi + (size_t)3 * HD * HD, WdhLo + (size_t)3 * HD * HD,
        dec_bih + 3 * HD, dec_bhh, dec_bhh + 3 * HD,
        DH32, DHhi, DHlo, RNN, PART, FL_D, EP_D, FLAGD);

    // ---- batched epilogue ----
    gemm_k<64, false, false><<<dim3(1, 1, NB), 256, 0, stream>>>(
        RNN, (int64_t)NB * HD, HD, PENC, (int64_t)NB * HD, HD,
        SC, (int64_t)NB * LI, LI, nullptr, 0, HD);
    softmax_k<<<dim3(LO * NB), dim3(64), 0, stream>>>(SC, attn_out);
    ctx_k<<<dim3(HD / 128, NB), dim3(256), 0, stream>>>(attn_out, EOUT, JIN);
    rnncopy_k<<<dim3(LO * NB * HD / 4 / 256), dim3(256), 0, stream>>>(RNN, JIN);
    gemm_k<128, true, true><<<dim3(HD / 128, LO * NB / 128, 1), 256, 0, stream>>>(
        JIN, 2 * HD, 0, joiner_W, 2 * HD, 0, VECS, HD, 0, joiner_b, 0, 2 * HD);
    gemm_k<128, true, false><<<dim3(NV / 128, LO * NB / 128, 1), 256, 0, stream>>>(
        VECS, HD, 0, proj_W, HD, 0, logits, NV, 0, proj_b, 0, HD);
}

// Round 9
// 5879.118 us; speedup vs baseline: 1.7988x; 1.0071x over previous
//
#include <hip/hip_runtime.h>
#include <hip/hip_bf16.h>
#include <stdint.h>

// ---- problem constants ----
constexpr int LI   = 128;    // L_IN
constexpr int LO   = 64;     // L_OUT
constexpr int NB   = 32;     // batch
constexpr int HD   = 1024;   // H
constexpr int HHD  = 512;    // HH
constexpr int NLAY = 2;
constexpr int NV   = 32000;  // V_OUT
constexpr int SOST = 1;

// FP32 tensors; bf16x3 split MFMA. Persistent recurrence: W in registers,
// h exchanged via agent-scope (L3) atomics. Round-9: CHANNEL-DISTRIBUTED
// barrier — per-block flags strided 8KB apart + 16 epoch replicas
// (round-8 counters showed barrier cost linear in nblk ~0.13us/block,
// i.e. arrival stores serializing on one memory channel).

typedef __hip_bfloat16 bf16;
typedef __attribute__((ext_vector_type(8))) short bf16x8;
typedef __attribute__((ext_vector_type(4))) float f32x4;
typedef unsigned long long u64;

constexpr int BSTR = 2048;   // flag stride in ints = 8 KB
constexpr int NEP  = 16;     // epoch replicas

__device__ __forceinline__ float b2f(bf16 x) { return __bfloat162float(x); }
__device__ __forceinline__ bf16  f2b(float x) { return __float2bfloat16(x); }
__device__ __forceinline__ float sigm(float x) { return 1.0f / (1.0f + expf(-x)); }

__device__ __forceinline__ f32x4 mfma(bf16x8 a, bf16x8 b, f32x4 c) {
    return __builtin_amdgcn_mfma_f32_16x16x32_bf16(a, b, c, 0, 0, 0);
}
__device__ __forceinline__ f32x4 mfma3(bf16x8 ah, bf16x8 al, bf16x8 bh, bf16x8 bl, f32x4 c) {
    c = mfma(ah, bh, c);
    c = mfma(ah, bl, c);
    c = mfma(al, bh, c);
    return c;
}
__device__ __forceinline__ bf16x8 ld8(const bf16* p) { return *(const bf16x8*)p; }

// ---- coherent (agent/L3) exchange helpers ----
__device__ __forceinline__ bf16x8 ldc(const bf16* p) {
    union { bf16x8 v; u64 q[2]; } u;
    u.q[0] = __hip_atomic_load((const u64*)p,     __ATOMIC_RELAXED, __HIP_MEMORY_SCOPE_AGENT);
    u.q[1] = __hip_atomic_load((const u64*)p + 1, __ATOMIC_RELAXED, __HIP_MEMORY_SCOPE_AGENT);
    return u.v;
}
__device__ __forceinline__ void stc2(bf16* p, bf16 a, bf16 b) {
    unsigned v = (unsigned)*(const unsigned short*)&a |
                 ((unsigned)*(const unsigned short*)&b << 16);
    __hip_atomic_store((unsigned*)p, v, __ATOMIC_RELAXED, __HIP_MEMORY_SCOPE_AGENT);
}
__device__ __forceinline__ f32x4 ldc4f(const float* p) {
    union { f32x4 v; u64 q[2]; } u;
    u.q[0] = __hip_atomic_load((const u64*)p,     __ATOMIC_RELAXED, __HIP_MEMORY_SCOPE_AGENT);
    u.q[1] = __hip_atomic_load((const u64*)p + 1, __ATOMIC_RELAXED, __HIP_MEMORY_SCOPE_AGENT);
    return u.v;
}
__device__ __forceinline__ void stc4f(float* p, f32x4 v) {
    union { f32x4 v; u64 q[2]; } u;
    u.v = v;
    __hip_atomic_store((u64*)p,     u.q[0], __ATOMIC_RELAXED, __HIP_MEMORY_SCOPE_AGENT);
    __hip_atomic_store((u64*)p + 1, u.q[1], __ATOMIC_RELAXED, __HIP_MEMORY_SCOPE_AGENT);
}

__device__ __forceinline__ void split8(const float* p, bf16x8& h8, bf16x8& l8) {
    #pragma unroll
    for (int j = 0; j < 8; j++) {
        float v = p[j];
        bf16 h = f2b(v);
        bf16 l = f2b(v - b2f(h));
        ((bf16*)&h8)[j] = h;
        ((bf16*)&l8)[j] = l;
    }
}

// ---- channel-distributed grid barrier: arrival store to 8KB-strided
// per-block flag (parallel across memory channels); master polls flags,
// releases 16 strided epoch replicas; consumers poll their own replica.
__device__ __forceinline__ void gbar2(int* __restrict__ flags, int* __restrict__ epoch,
                                      int nblk, int myid, int val, bool master) {
    __syncthreads();
    const int tid = threadIdx.x;
    if (tid < 64) {   // wave 0
        if (tid == 0) {
            asm volatile("s_waitcnt vmcnt(0)" ::: "memory");
            __hip_atomic_store(&flags[myid * BSTR], val, __ATOMIC_RELAXED, __HIP_MEMORY_SCOPE_AGENT);
        }
        if (master) {
            bool done = false;
            while (!done) {
                bool ok = true;
                for (int i = tid; i < nblk; i += 64)
                    ok &= (__hip_atomic_load(&flags[i * BSTR], __ATOMIC_RELAXED, __HIP_MEMORY_SCOPE_AGENT) >= val);
                done = __all(ok);
                if (!done) __builtin_amdgcn_s_sleep(1);
            }
            if (tid < NEP)
                __hip_atomic_store(&epoch[tid * BSTR], val, __ATOMIC_RELAXED, __HIP_MEMORY_SCOPE_AGENT);
        } else if (tid == 0) {
            int* ep = &epoch[(myid & (NEP - 1)) * BSTR];
            while (__hip_atomic_load(ep, __ATOMIC_RELAXED, __HIP_MEMORY_SCOPE_AGENT) < val)
                __builtin_amdgcn_s_sleep(1);
        }
        asm volatile("" ::: "memory");
    }
    __syncthreads();
}

// =====================================================================
// Split-precision MFMA GEMM (unchanged).
// =====================================================================
template<int BM, bool BIAS, bool TANH>
__global__ __launch_bounds__(256) void gemm_k(
    const float* __restrict__ A, int64_t lda, int64_t sA,
    const float* __restrict__ W, int64_t ldw, int64_t sW,
    float* __restrict__ C, int64_t ldc, int64_t sC,
    const float* __restrict__ bias, int64_t sBias,
    int K)
{
    constexpr int FM = BM / 32;
    __shared__ __align__(16) bf16 Ahi[BM * 32], Alo[BM * 32];
    __shared__ __align__(16) bf16 Whi[128 * 32], Wlo[128 * 32];
    const int z    = blockIdx.z;
    const float* Ab = A + (int64_t)z * sA;
    const float* Wb = W + (int64_t)z * sW;
    const int n0   = blockIdx.x * 128;
    const int m0   = blockIdx.y * BM;
    const int tid  = threadIdx.x;
    const int lane = tid & 63, wid = tid >> 6;
    const int wm   = wid >> 1, wn = wid & 1;
    const int srow = lane >> 2;
    const int skb  = (lane & 3) * 8;
    const int r16  = lane & 15;
    const int k8   = (lane >> 4) * 8;

    f32x4 acc[FM][4];
    #pragma unroll
    for (int i = 0; i < FM; i++)
        #pragma unroll
        for (int j = 0; j < 4; j++)
            acc[i][j] = f32x4{0.f, 0.f, 0.f, 0.f};

    for (int k0 = 0; k0 < K; k0 += 32) {
        for (int c = wid; c < BM / 16; c += 4) {
            bf16x8 h8, l8;
            split8(Ab + (int64_t)(m0 + c * 16 + srow) * lda + k0 + skb, h8, l8);
            *(bf16x8*)(Ahi + c * 512 + lane * 8) = h8;
            *(bf16x8*)(Alo + c * 512 + lane * 8) = l8;
        }
        for (int c = wid; c < 8; c += 4) {
            bf16x8 h8, l8;
            split8(Wb + (int64_t)(n0 + c * 16 + srow) * ldw + k0 + skb, h8, l8);
            *(bf16x8*)(Whi + c * 512 + lane * 8) = h8;
            *(bf16x8*)(Wlo + c * 512 + lane * 8) = l8;
        }
        __syncthreads();
        bf16x8 afh[FM], afl[FM], wfh[4], wfl[4];
        #pragma unroll
        for (int mt = 0; mt < FM; mt++) {
            const int off = (wm * (BM / 2) + mt * 16 + r16) * 32 + k8;
            afh[mt] = ld8(Ahi + off);
            afl[mt] = ld8(Alo + off);
        }
        #pragma unroll
        for (int nt = 0; nt < 4; nt++) {
            const int off = (wn * 64 + nt * 16 + r16) * 32 + k8;
            wfh[nt] = ld8(Whi + off);
            wfl[nt] = ld8(Wlo + off);
        }
        #pragma unroll
        for (int mt = 0; mt < FM; mt++)
            #pragma unroll
            for (int nt = 0; nt < 4; nt++)
                acc[mt][nt] = mfma3(afh[mt], afl[mt], wfh[nt], wfl[nt], acc[mt][nt]);
        __syncthreads();
    }
    #pragma unroll
    for (int nt = 0; nt < 4; nt++) {
        const int n = n0 + wn * 64 + nt * 16 + r16;
        float bv = 0.f;
        if constexpr (BIAS) bv = bias[(int64_t)z * sBias + n];
        #pragma unroll
        for (int mt = 0; mt < FM; mt++) {
            const int mb = m0 + wm * (BM / 2) + mt * 16 + (lane >> 4) * 4;
            #pragma unroll
            for (int r = 0; r < 4; r++) {
                float v = acc[mt][nt][r] + bv;
                if constexpr (TANH) v = tanhf(v);
                C[(int64_t)z * sC + (int64_t)(mb + r) * ldc + n] = v;
            }
        }
    }
}

__global__ void presplit_k(const float* __restrict__ x, bf16* __restrict__ hi,
                           bf16* __restrict__ lo, int n)
{
    const int i = blockIdx.x * 256 + threadIdx.x;
    if (i < n) {
        float v = x[i];
        bf16 h = f2b(v);
        hi[i] = h;
        lo[i] = f2b(v - b2f(h));
    }
}

__global__ void embed_k(const int* __restrict__ toks, const float* __restrict__ tab,
                        float* __restrict__ out, int shifted)
{
    const int row = blockIdx.x;
    int tok;
    if (shifted) {
        const int t = row / NB, b = row - t * NB;
        tok = (t == 0) ? SOST : toks[(t - 1) * NB + b];
    } else {
        tok = toks[row];
    }
    const uint4* s = (const uint4*)(tab + (int64_t)tok * HD);
    uint4* d = (uint4*)(out + (int64_t)row * HD);
    d[threadIdx.x] = s[threadIdx.x];
}

// =====================================================================
// Persistent encoder layer, W in registers, coherent h exchange,
// distributed flag/epoch barrier. Grid (HHD/16=32, 2 dirs) x 256 thr.
// =====================================================================
__global__ __launch_bounds__(256, 1) void enc_persist_k(
    const float* __restrict__ gi,
    const bf16* __restrict__ whhHi,
    const bf16* __restrict__ whhLo,
    const float* __restrict__ bhh,
    float* __restrict__ h32,
    bf16* __restrict__ hHi, bf16* __restrict__ hLo,
    float* __restrict__ Y,
    float* __restrict__ dh32, bf16* __restrict__ dhHi, bf16* __restrict__ dhLo,
    int* __restrict__ flags, int* __restrict__ epoch)
{
    __shared__ f32x4 red[4][6][64];
    const int d = blockIdx.y;
    const int j0 = blockIdx.x * 16;
    const int tid = threadIdx.x;
    const int lane = tid & 63, wid = tid >> 6;
    const int r16 = lane & 15, k8 = (lane >> 4) * 8;
    const int kq = wid * 128;
    const bf16* WdH = whhHi + (int64_t)d * 3 * HHD * HHD;
    const bf16* WdL = whhLo + (int64_t)d * 3 * HHD * HHD;
    const int j = j0 + r16;
    const int myid = d * 32 + blockIdx.x;
    const bool master = (myid == 0);

    bf16x8 wh[3][4], wl[3][4];
    #pragma unroll
    for (int g = 0; g < 3; g++)
        #pragma unroll
        for (int kk = 0; kk < 4; kk++) {
            const int64_t wo = (int64_t)(g * HHD + j0 + r16) * HHD + kq + kk * 32 + k8;
            wh[g][kk] = ld8(WdH + wo);
            wl[g][kk] = ld8(WdL + wo);
        }
    const float br = bhh[d * 3 * HHD + j];
    const float bz = bhh[d * 3 * HHD + HHD + j];
    const float bn = bhh[d * 3 * HHD + 2 * HHD + j];

    for (int s = 0; s < LI; s++) {
        const int t = d ? (LI - 1 - s) : s;
        const int par = s & 1, npar = par ^ 1;
        const int64_t hbase = (int64_t)(par * 2 + d) * NB * HHD;

        f32x4 acc[2][3];
        #pragma unroll
        for (int m = 0; m < 2; m++)
            #pragma unroll
            for (int g = 0; g < 3; g++) acc[m][g] = f32x4{0.f, 0.f, 0.f, 0.f};

        #pragma unroll
        for (int kk = 0; kk < 4; kk++) {
            const int64_t o0 = hbase + (int64_t)r16 * HHD + kq + kk * 32 + k8;
            const int64_t o1 = hbase + (int64_t)(16 + r16) * HHD + kq + kk * 32 + k8;
            bf16x8 a0h = ldc(hHi + o0), a0l = ldc(hLo + o0);
            bf16x8 a1h = ldc(hHi + o1), a1l = ldc(hLo + o1);
            #pragma unroll
            for (int g = 0; g < 3; g++) {
                acc[0][g] = mfma3(a0h, a0l, wh[g][kk], wl[g][kk], acc[0][g]);
                acc[1][g] = mfma3(a1h, a1l, wh[g][kk], wl[g][kk], acc[1][g]);
            }
        }
        #pragma unroll
        for (int m = 0; m < 2; m++)
            #pragma unroll
            for (int g = 0; g < 3; g++)
                red[wid][m * 3 + g][lane] = acc[m][g];
        __syncthreads();
        if (wid == 0) {
            f32x4 a2[2][3];
            #pragma unroll
            for (int m = 0; m < 2; m++)
                #pragma unroll
                for (int g = 0; g < 3; g++)
                    a2[m][g] = red[0][m * 3 + g][lane] + red[1][m * 3 + g][lane]
                             + red[2][m * 3 + g][lane] + red[3][m * 3 + g][lane];
            const float* gid = gi + ((int64_t)d * LI * NB + (int64_t)t * NB) * (3 * HHD);
            #pragma unroll
            for (int mt = 0; mt < 2; mt++)
                #pragma unroll
                for (int r = 0; r < 4; r++) {
                    const int b = mt * 16 + (lane >> 4) * 4 + r;
                    const float ir  = gid[b * 3 * HHD + j];
                    const float iz  = gid[b * 3 * HHD + HHD + j];
                    const float inn = gid[b * 3 * HHD + 2 * HHD + j];
                    const float rg = sigm(ir + a2[mt][0][r] + br);
                    const float zg = sigm(iz + a2[mt][1][r] + bz);
                    const float ng = tanhf(inn + rg * (a2[mt][2][r] + bn));
                    const float hold = h32[hbase + (int64_t)b * HHD + j];
                    const float hnew = (1.f - zg) * ng + zg * hold;
                    const int64_t no = (int64_t)(npar * 2 + d) * NB * HHD + (int64_t)b * HHD + j;
                    bf16 hh = f2b(hnew);
                    bf16 hl = f2b(hnew - b2f(hh));
                    h32[no] = hnew;
                    const float hn2 = __shfl_xor(hnew, 1);
                    if (!(lane & 1)) {
                        bf16 hh2 = f2b(hn2);
                        bf16 hl2 = f2b(hn2 - b2f(hh2));
                        stc2(hHi + no, hh, hh2);
                        stc2(hLo + no, hl, hl2);
                    }
                    Y[((int64_t)t * NB + b) * HD + d * HHD + j] = hnew;
                    if (s == LI - 1) {
                        const int64_t dof = (int64_t)b * HD + d * HHD + j;
                        dh32[dof] = hnew;
                        dhHi[dof] = hh;
                        dhLo[dof] = hl;
                    }
                }
        }
        if (s < LI - 1) gbar2(flags, epoch, 64, myid, s + 1, master);
    }
}

// =====================================================================
// Persistent decoder, W in registers, coherent exchange, distributed
// flag/epoch barrier; kh0<->kh1 PART hand-off via 8KB-strided flags.
// Grid (HD/16=64, 3) x 512 thr.
// =====================================================================
__global__ __launch_bounds__(512, 1) void dec_persist_k(
    const float* __restrict__ gi0,
    const bf16* __restrict__ wih1Hi, const bf16* __restrict__ wih1Lo,
    const bf16* __restrict__ whh0Hi, const bf16* __restrict__ whh0Lo,
    const bf16* __restrict__ whh1Hi, const bf16* __restrict__ whh1Lo,
    const float* __restrict__ bih1,
    const float* __restrict__ bhh0,
    const float* __restrict__ bhh1,
    float* __restrict__ h32,
    bf16* __restrict__ hHi, bf16* __restrict__ hLo,
    float* __restrict__ rnn,
    f32x4* __restrict__ part,
    int* __restrict__ flags, int* __restrict__ epoch,
    int* __restrict__ flagd)
{
    __shared__ f32x4 red[8][8][64];
    const int tid = threadIdx.x;
    const int lane = tid & 63, wid = tid >> 6;
    const int r16 = lane & 15, k8 = (lane >> 4) * 8;
    const int j0 = blockIdx.x * 16;
    const int j = j0 + r16;
    const int NBLK = 64 * 3;
    const int myid = blockIdx.y * 64 + blockIdx.x;
    const bool master = (myid == 0);

    if (blockIdx.y == 0) {
        const int kq = wid * 128;
        bf16x8 wh[3][4], wl[3][4];
        #pragma unroll
        for (int g = 0; g < 3; g++)
            #pragma unroll
            for (int kk = 0; kk < 4; kk++) {
                const int64_t wo = (int64_t)(g * HD + j0 + r16) * HD + kq + kk * 32 + k8;
                wh[g][kk] = ld8(whh0Hi + wo);
                wl[g][kk] = ld8(whh0Lo + wo);
            }
        const float b0r = bhh0[j], b0z = bhh0[HD + j], b0n = bhh0[2 * HD + j];

        for (int s = 0; s <= LO; s++) {
            if (s < LO) {
                const int t = s, par = t & 1, npar = par ^ 1;
                const int64_t hb = (int64_t)(par * NLAY + 0) * NB * HD;
                f32x4 acc[2][3];
                #pragma unroll
                for (int m = 0; m < 2; m++)
                    #pragma unroll
                    for (int g = 0; g < 3; g++) acc[m][g] = f32x4{0.f, 0.f, 0.f, 0.f};
                #pragma unroll
                for (int kk = 0; kk < 4; kk++) {
                    const int64_t o0 = hb + (int64_t)r16 * HD + kq + kk * 32 + k8;
                    const int64_t o1 = hb + (int64_t)(16 + r16) * HD + kq + kk * 32 + k8;
                    bf16x8 a0h = ldc(hHi + o0), a0l = ldc(hLo + o0);
                    bf16x8 a1h = ldc(hHi + o1), a1l = ldc(hLo + o1);
                    #pragma unroll
                    for (int g = 0; g < 3; g++) {
                        acc[0][g] = mfma3(a0h, a0l, wh[g][kk], wl[g][kk], acc[0][g]);
                        acc[1][g] = mfma3(a1h, a1l, wh[g][kk], wl[g][kk], acc[1][g]);
                    }
                }
                #pragma unroll
                for (int m = 0; m < 2; m++)
                    #pragma unroll
                    for (int g = 0; g < 3; g++)
                        red[wid][m * 3 + g][lane] = acc[m][g];
                __syncthreads();
                if (wid == 0) {
                    f32x4 a2[2][3];
                    #pragma unroll
                    for (int m = 0; m < 2; m++)
                        #pragma unroll
                        for (int g = 0; g < 3; g++) {
                            f32x4 v = red[0][m * 3 + g][lane];
                            #pragma unroll
                            for (int w2 = 1; w2 < 8; w2++) v += red[w2][m * 3 + g][lane];
                            a2[m][g] = v;
                        }
                    const float* gid = gi0 + (int64_t)t * NB * 3 * HD;
                    #pragma unroll
                    for (int mt = 0; mt < 2; mt++)
                        #pragma unroll
                        for (int r = 0; r < 4; r++) {
                            const int b = mt * 16 + (lane >> 4) * 4 + r;
                            const float ir  = gid[b * 3 * HD + j];
                            const float iz  = gid[b * 3 * HD + HD + j];
                            const float inn = gid[b * 3 * HD + 2 * HD + j];
                            const float rg = sigm(ir + a2[mt][0][r] + b0r);
                            const float zg = sigm(iz + a2[mt][1][r] + b0z);
                            const float ng = tanhf(inn + rg * (a2[mt][2][r] + b0n));
                            const float hold = h32[hb + (int64_t)b * HD + j];
                            const float hnew = (1.f - zg) * ng + zg * hold;
                            const int64_t no = (int64_t)(npar * NLAY + 0) * NB * HD + (int64_t)b * HD + j;
                            bf16 hh = f2b(hnew);
                            bf16 hl = f2b(hnew - b2f(hh));
                            h32[no] = hnew;
                            const float hn2 = __shfl_xor(hnew, 1);
                            if (!(lane & 1)) {
                                bf16 hh2 = f2b(hn2);
                                bf16 hl2 = f2b(hn2 - b2f(hh2));
                                stc2(hHi + no, hh, hh2);
                                stc2(hLo + no, hl, hl2);
                            }
                        }
                }
            }
            if (s < LO) gbar2(flags, epoch, NBLK, myid, s + 1, master);
        }
    } else {
        const int kh = blockIdx.y - 1;
        const int kb = kh * 512 + wid * 64;
        bf16x8 wIh[3][2], wIl[3][2], wHh[3][2], wHl[3][2];
        #pragma unroll
        for (int g = 0; g < 3; g++)
            #pragma unroll
            for (int kk = 0; kk < 2; kk++) {
                const int64_t wo = (int64_t)(g * HD + j0 + r16) * HD + kb + kk * 32 + k8;
                wIh[g][kk] = ld8(wih1Hi + wo);
                wIl[g][kk] = ld8(wih1Lo + wo);
                wHh[g][kk] = ld8(whh1Hi + wo);
                wHl[g][kk] = ld8(whh1Lo + wo);
            }
        const float brr = bih1[j] + bhh1[j];
        const float bzz = bih1[HD + j] + bhh1[HD + j];
        const float bin = bih1[2 * HD + j];
        const float bhn = bhh1[2 * HD + j];

        for (int s = 0; s <= LO; s++) {
            if (s >= 1) {
                const int t = s - 1;
                const int p0 = (t + 1) & 1;
                const int p1 = t & 1, np1 = p1 ^ 1;
                const int64_t h0b = (int64_t)(p0 * NLAY + 0) * NB * HD;
                const int64_t h1b = (int64_t)(p1 * NLAY + 1) * NB * HD;
                f32x4 arz[2][2], ain[2], ahn[2];
                #pragma unroll
                for (int i = 0; i < 2; i++) {
                    arz[i][0] = f32x4{0.f, 0.f, 0.f, 0.f};
                    arz[i][1] = f32x4{0.f, 0.f, 0.f, 0.f};
                    ain[i] = f32x4{0.f, 0.f, 0.f, 0.f};
                    ahn[i] = f32x4{0.f, 0.f, 0.f, 0.f};
                }
                #pragma unroll
                for (int kk = 0; kk < 2; kk++) {
                    const int64_t xo0 = h0b + (int64_t)r16 * HD + kb + kk * 32 + k8;
                    const int64_t xo1 = h0b + (int64_t)(16 + r16) * HD + kb + kk * 32 + k8;
                    const int64_t yo0 = h1b + (int64_t)r16 * HD + kb + kk * 32 + k8;
                    const int64_t yo1 = h1b + (int64_t)(16 + r16) * HD + kb + kk * 32 + k8;
                    bf16x8 x0h = ldc(hHi + xo0), x0l = ldc(hLo + xo0);
                    bf16x8 x1h = ldc(hHi + xo1), x1l = ldc(hLo + xo1);
                    bf16x8 y0h = ldc(hHi + yo0), y0l = ldc(hLo + yo0);
                    bf16x8 y1h = ldc(hHi + yo1), y1l = ldc(hLo + yo1);
                    arz[0][0] = mfma3(x0h, x0l, wIh[0][kk], wIl[0][kk], arz[0][0]);
                    arz[0][0] = mfma3(y0h, y0l, wHh[0][kk], wHl[0][kk], arz[0][0]);
                    arz[1][0] = mfma3(x1h, x1l, wIh[0][kk], wIl[0][kk], arz[1][0]);
                    arz[1][0] = mfma3(y1h, y1l, wHh[0][kk], wHl[0][kk], arz[1][0]);
                    arz[0][1] = mfma3(x0h, x0l, wIh[1][kk], wIl[1][kk], arz[0][1]);
                    arz[0][1] = mfma3(y0h, y0l, wHh[1][kk], wHl[1][kk], arz[0][1]);
                    arz[1][1] = mfma3(x1h, x1l, wIh[1][kk], wIl[1][kk], arz[1][1]);
                    arz[1][1] = mfma3(y1h, y1l, wHh[1][kk], wHl[1][kk], arz[1][1]);
                    ain[0] = mfma3(x0h, x0l, wIh[2][kk], wIl[2][kk], ain[0]);
                    ain[1] = mfma3(x1h, x1l, wIh[2][kk], wIl[2][kk], ain[1]);
                    ahn[0] = mfma3(y0h, y0l, wHh[2][kk], wHl[2][kk], ahn[0]);
                    ahn[1] = mfma3(y1h, y1l, wHh[2][kk], wHl[2][kk], ahn[1]);
                }
                red[wid][0][lane] = arz[0][0];
                red[wid][1][lane] = arz[1][0];
                red[wid][2][lane] = arz[0][1];
                red[wid][3][lane] = arz[1][1];
                red[wid][4][lane] = ain[0];
                red[wid][5][lane] = ain[1];
                red[wid][6][lane] = ahn[0];
                red[wid][7][lane] = ahn[1];
                __syncthreads();
                if (wid == 0) {
                    f32x4 p[8];
                    #pragma unroll
                    for (int grp = 0; grp < 8; grp++) {
                        f32x4 v = red[0][grp][lane];
                        #pragma unroll
                        for (int w2 = 1; w2 < 8; w2++) v += red[w2][grp][lane];
                        p[grp] = v;
                    }
                    if (kh == 1) {
                        #pragma unroll
                        for (int grp = 0; grp < 8; grp++)
                            stc4f((float*)&part[((size_t)blockIdx.x * 8 + grp) * 64 + lane], p[grp]);
                        asm volatile("s_waitcnt vmcnt(0)" ::: "memory");
                        if (lane == 0)
                            __hip_atomic_store(&flagd[blockIdx.x * BSTR], s, __ATOMIC_RELAXED, __HIP_MEMORY_SCOPE_AGENT);
                    } else {
                        while (__hip_atomic_load(&flagd[blockIdx.x * BSTR], __ATOMIC_RELAXED, __HIP_MEMORY_SCOPE_AGENT) < s)
                            __builtin_amdgcn_s_sleep(1);
                        asm volatile("" ::: "memory");
                        #pragma unroll
                        for (int grp = 0; grp < 8; grp++)
                            p[grp] += ldc4f((const float*)&part[((size_t)blockIdx.x * 8 + grp) * 64 + lane]);
                        #pragma unroll
                        for (int mt = 0; mt < 2; mt++)
                            #pragma unroll
                            for (int r = 0; r < 4; r++) {
                                const int b = mt * 16 + (lane >> 4) * 4 + r;
                                const float rg = sigm(p[0 + mt][r] + brr);
                                const float zg = sigm(p[2 + mt][r] + bzz);
                                const float ng = tanhf(p[4 + mt][r] + bin + rg * (p[6 + mt][r] + bhn));
                                const float hold = h32[h1b + (int64_t)b * HD + j];
                                const float hnew = (1.f - zg) * ng + zg * hold;
                                const int64_t no = (int64_t)(np1 * NLAY + 1) * NB * HD + (int64_t)b * HD + j;
                                bf16 hh = f2b(hnew);
                                bf16 hl = f2b(hnew - b2f(hh));
                                h32[no] = hnew;
                                const float hn2 = __shfl_xor(hnew, 1);
                                if (!(lane & 1)) {
                                    bf16 hh2 = f2b(hn2);
                                    bf16 hl2 = f2b(hn2 - b2f(hh2));
                                    stc2(hHi + no, hh, hh2);
                                    stc2(hLo + no, hl, hl2);
                                }
                                rnn[((int64_t)t * NB + b) * HD + j] = hnew;
                            }
                    }
                }
            }
            if (s < LO) gbar2(flags, epoch, NBLK, myid, s + 1, master);
        }
    }
}

// =====================================================================
__global__ __launch_bounds__(64) void softmax_k(const float* __restrict__ sc,
                                                float* __restrict__ aout)
{
    const int row = blockIdx.x, l = threadIdx.x;
    float v0 = sc[row * LI + l], v1 = sc[row * LI + 64 + l];
    float m = fmaxf(v0, v1);
    #pragma unroll
    for (int o = 32; o > 0; o >>= 1) m = fmaxf(m, __shfl_xor(m, o));
    float e0 = expf(v0 - m), e1 = expf(v1 - m);
    float s = e0 + e1;
    #pragma unroll
    for (int o = 32; o > 0; o >>= 1) s += __shfl_xor(s, o);
    const float inv = 1.f / s;
    aout[row * LI + l] = e0 * inv;
    aout[row * LI + 64 + l] = e1 * inv;
}

__global__ __launch_bounds__(256) void ctx_k(const float* __restrict__ at,
                                             const float* __restrict__ enc,
                                             float* __restrict__ jin)
{
    const int b = blockIdx.y, h0 = blockIdx.x * 128;
    __shared__ __align__(16) float al[LO][LI];
    for (int i = threadIdx.x; i < LO * LI; i += 256) {
        const int to = i >> 7, ti = i & 127;
        al[to][ti] = at[(to * NB + b) * LI + ti];
    }
    __syncthreads();
    const int hc = h0 + (threadIdx.x & 127);
    const int rh = threadIdx.x >> 7;
    float acc[32];
    #pragma unroll
    for (int i = 0; i < 32; i++) acc[i] = 0.f;
    for (int t = 0; t < LI; t++) {
        const float ev = enc[((int64_t)t * NB + b) * HD + hc];
        #pragma unroll
        for (int i = 0; i < 32; i++) acc[i] += ev * al[rh * 32 + i][t];
    }
    #pragma unroll
    for (int i = 0; i < 32; i++)
        jin[((int64_t)(rh * 32 + i) * NB + b) * (2 * HD) + hc] = acc[i];
}

__global__ void rnncopy_k(const float* __restrict__ rnn, float* __restrict__ jin)
{
    const int idx = blockIdx.x * 256 + threadIdx.x;
    const int row = idx >> 8;
    const int c = idx & 255;
    ((uint4*)jin)[(int64_t)row * 512 + 256 + c] = ((const uint4*)rnn)[idx];
}

// =====================================================================
extern "C" void kernel_launch(void* const* d_in, const int* in_sizes, int n_in,
                              void* d_out, int out_size, void* d_ws, size_t ws_size,
                              hipStream_t stream)
{
    (void)in_sizes; (void)n_in; (void)out_size; (void)ws_size;
    const int*   in_tok   = (const int*)d_in[0];
    const int*   out_tok  = (const int*)d_in[2];
    const float* enc_emb  = (const float*)d_in[4];
    const float* enc_wih  = (const float*)d_in[5];
    const float* enc_whh  = (const float*)d_in[6];
    const float* enc_bih  = (const float*)d_in[7];
    const float* enc_bhh  = (const float*)d_in[8];
    const float* dec_emb  = (const float*)d_in[9];
    const float* dec_wih  = (const float*)d_in[10];
    const float* dec_whh  = (const float*)d_in[11];
    const float* dec_bih  = (const float*)d_in[12];
    const float* dec_bhh  = (const float*)d_in[13];
    const float* attn_W   = (const float*)d_in[14];
    const float* joiner_W = (const float*)d_in[15];
    const float* joiner_b = (const float*)d_in[16];
    const float* proj_W   = (const float*)d_in[17];
    const float* proj_b   = (const float*)d_in[18];
    float* logits   = (float*)d_out;
    float* attn_out = logits + (size_t)LO * NB * NV;

    const size_t MB = 1ull << 20;
    char* o = (char*)d_out;   // logits region alone is 262 MiB fp32
    float* XB0   = (float*)(o);              // 16 MiB enc embedded input
    float* XB1   = (float*)(o + 16 * MB);    // 16 MiB enc layer0 output
    float* EOUT  = (float*)(o + 32 * MB);    // 16 MiB enc_outputs
    float* PENC  = (float*)(o + 48 * MB);    // 16 MiB proj_enc
    float* GI    = (float*)(o + 64 * MB);    // 48 MiB enc gi (both dirs)
    float* DEMB  = (float*)(o + 112 * MB);   //  8 MiB dec embedded
    float* DGI0  = (float*)(o + 120 * MB);   // 24 MiB dec layer0 gi
    float* RNN   = (float*)(o + 144 * MB);   //  8 MiB rnn_out
    float* SC    = (float*)(o + 152 * MB);   //  1 MiB scores
    float* JIN   = (float*)(o + 153 * MB);   // 16 MiB cat(ctx, rnn)
    bf16* WencHi = (bf16*)(o + 169 * MB);    //  6 MiB enc_whh hi
    bf16* WencLo = (bf16*)(o + 175 * MB);    //  6 MiB enc_whh lo
    bf16* WdhHi  = (bf16*)(o + 181 * MB);    // 12 MiB dec_whh hi
    bf16* WdhLo  = (bf16*)(o + 193 * MB);    // 12 MiB dec_whh lo
    bf16* Wih1Hi = (bf16*)(o + 205 * MB);    //  6 MiB dec_wih[1] hi
    bf16* Wih1Lo = (bf16*)(o + 211 * MB);    //  6 MiB dec_wih[1] lo
    f32x4* PART  = (f32x4*)(o + 219 * MB);   // 512 KiB layer1 partials
    // ---- barrier arena: 8KB-strided flags + 16 epoch replicas ----
    char* ba = o + 220 * MB;                 // 4 MiB total, < 262 MiB
    int*  FL_E0  = (int*)(ba);                       // 64 x 8KB = 512 KiB
    int*  EP_E0  = (int*)(ba + 512 * 1024);          // 16 x 8KB = 128 KiB
    int*  FL_E1  = (int*)(ba + 640 * 1024);          // 512 KiB
    int*  EP_E1  = (int*)(ba + 1152 * 1024);         // 128 KiB
    int*  FL_D   = (int*)(ba + 1280 * 1024);         // 192 x 8KB = 1536 KiB
    int*  EP_D   = (int*)(ba + 2816 * 1024);         // 128 KiB
    int*  FLAGD  = (int*)(ba + 2944 * 1024);         // 64 x 8KB = 512 KiB

    char* w = (char*)d_ws;                   // 10 MiB total
    float* VECS = (float*)(w);                       // 8 MiB tanh(joiner)
    float* EH32 = (float*)(w + 8 * MB);              // 512 KiB
    bf16*  EHhi = (bf16*) (w + 8 * MB + 524288);     // 256 KiB
    bf16*  EHlo = (bf16*) (w + 8 * MB + 786432);     // 256 KiB
    float* DH32 = (float*)(w + 9 * MB);              // 512 KiB
    bf16*  DHhi = (bf16*) (w + 9 * MB + 524288);     // 256 KiB
    bf16*  DHlo = (bf16*) (w + 9 * MB + 786432);     // 256 KiB

    hipMemsetAsync(ba, 0, 4 * MB, stream);

    // ---- pre-split recurrent weights ----
    const int nEnc = NLAY * 2 * 3 * HHD * HHD;
    const int nDhh = NLAY * 3 * HD * HD;
    const int nIh1 = 3 * HD * HD;
    presplit_k<<<dim3((nEnc + 255) / 256), dim3(256), 0, stream>>>(enc_whh, WencHi, WencLo, nEnc);
    presplit_k<<<dim3((nDhh + 255) / 256), dim3(256), 0, stream>>>(dec_whh, WdhHi, WdhLo, nDhh);
    presplit_k<<<dim3((nIh1 + 255) / 256), dim3(256), 0, stream>>>(dec_wih + (size_t)3 * HD * HD, Wih1Hi, Wih1Lo, nIh1);

    // ---- decoder prep ----
    embed_k<<<dim3(LO * NB), dim3(256), 0, stream>>>(out_tok, dec_emb, DEMB, 1);
    gemm_k<128, true, false><<<dim3(3 * HD / 128, LO * NB / 128, 1), 256, 0, stream>>>(
        DEMB, HD, 0, dec_wih, HD, 0, DGI0, 3 * HD, 0, dec_bih, 0, HD);

    // ---- encoder ----
    embed_k<<<dim3(LI * NB), dim3(256), 0, stream>>>(in_tok, enc_emb, XB0, 0);
    for (int l = 0; l < NLAY; l++) {
        const float* Xin = l ? XB1 : XB0;
        float* Yout = l ? EOUT : XB1;
        hipMemsetAsync(EH32, 0, (size_t)2 * 2 * NB * HHD * 4, stream);
        hipMemsetAsync(EHhi, 0, (size_t)2 * 2 * NB * HHD * 2, stream);
        hipMemsetAsync(EHlo, 0, (size_t)2 * 2 * NB * HHD * 2, stream);
        gemm_k<128, true, false><<<dim3(3 * HHD / 128, LI * NB / 128, 2), 256, 0, stream>>>(
            Xin, HD, 0,
            enc_wih + (size_t)l * 2 * 3 * HHD * HD, HD, (int64_t)3 * HHD * HD,
            GI, 3 * HHD, (int64_t)LI * NB * 3 * HHD,
            enc_bih + l * 2 * 3 * HHD, 3 * HHD, HD);
        enc_persist_k<<<dim3(HHD / 16, 2), dim3(256), 0, stream>>>(
            GI,
            WencHi + (size_t)l * 2 * 3 * HHD * HHD,
            WencLo + (size_t)l * 2 * 3 * HHD * HHD,
            enc_bhh + l * 2 * 3 * HHD,
            EH32, EHhi, EHlo, Yout,
            DH32 + (size_t)l * NB * HD, DHhi + (size_t)l * NB * HD,
            DHlo + (size_t)l * NB * HD,
            l ? FL_E1 : FL_E0, l ? EP_E1 : EP_E0);
    }

    // proj_enc = enc_outputs @ attn_W^T
    gemm_k<128, false, false><<<dim3(HD / 128, LI * NB / 128, 1), 256, 0, stream>>>(
        EOUT, HD, 0, attn_W, HD, 0, PENC, HD, 0, nullptr, 0, HD);

    // ---- decoder recurrence (persistent) ----
    dec_persist_k<<<dim3(HD / 16, 3), dim3(512), 0, stream>>>(
        DGI0,
        Wih1Hi, Wih1Lo,
        WdhHi, WdhLo,
        WdhHi + (size_t)3 * HD * HD, WdhLo + (size_t)3 * HD * HD,
        dec_bih + 3 * HD, dec_bhh, dec_bhh + 3 * HD,
        DH32, DHhi, DHlo, RNN, PART, FL_D, EP_D, FLAGD);

    // ---- batched epilogue ----
    gemm_k<64, false, false><<<dim3(1, 1, NB), 256, 0, stream>>>(
        RNN, (int64_t)NB * HD, HD, PENC, (int64_t)NB * HD, HD,
        SC, (int64_t)NB * LI, LI, nullptr, 0, HD);
    softmax_k<<<dim3(LO * NB), dim3(64), 0, stream>>>(SC, attn_out);
    ctx_k<<<dim3(HD / 128, NB), dim3(256), 0, stream>>>(attn_out, EOUT, JIN);
    rnncopy_k<<<dim3(LO * NB * HD / 4 / 256), dim3(256), 0, stream>>>(RNN, JIN);
    gemm_k<128, true, true><<<dim3(HD / 128, LO * NB / 128, 1), 256, 0, stream>>>(
        JIN, 2 * HD, 0, joiner_W, 2 * HD, 0, VECS, HD, 0, joiner_b, 0, 2 * HD);
    gemm_k<128, true, false><<<dim3(NV / 128, LO * NB / 128, 1), 256, 0, stream>>>(
        VECS, HD, 0, proj_W, HD, 0, logits, NV, 0, proj_b, 0, HD);
}